// Round 15
// baseline (398.125 us; speedup 1.0000x reference)
//
#include <hip/hip_runtime.h>
#include <cstdint>
#include <cstddef>

static constexpr int Bn  = 16;
static constexpr int Nn  = 2048;
static constexpr int NHn = 64;
static constexpr int K1  = 1024;
static constexpr int K2  = 512;

// ---------------- threefry2x32 (exact JAX semantics; verified via out0) ----------------
__host__ __device__ inline void tf2x32(uint32_t k0, uint32_t k1, uint32_t& x0, uint32_t& x1) {
  const uint32_t ks0 = k0, ks1 = k1, ks2 = k0 ^ k1 ^ 0x1BD11BDAu;
  x0 += ks0; x1 += ks1;
  const int R[20] = {13,15,26,6, 17,29,16,24, 13,15,26,6, 17,29,16,24, 13,15,26,6};
  const uint32_t ks[3] = {ks0, ks1, ks2};
  int inj = 0;
  for (int r = 0; r < 20; ++r) {
    x0 += x1;
    x1 = (x1 << R[r]) | (x1 >> (32 - R[r]));
    x1 ^= x0;
    if ((r & 3) == 3) {
      ++inj;
      x0 += ks[inj % 3];
      x1 += ks[(inj + 1) % 3] + (uint32_t)inj;
    }
  }
}

// ---------------- XLA CPU f32 exp (GenerateVF32Exp / Eigen pexp, Cephes, FMA) ----------
__device__ __forceinline__ float xla_expf(float x) {
  const float LOG2EF   = 1.44269504088896341f;
  const float ln2_hi   = 0.693359375f;
  const float nln2_lo  = 2.12194440e-4f;     // -(ln2 - ln2_hi)
  const float p0 = 1.9875691500e-4f, p1c = 1.3981999507e-3f, p2c = 8.3334519073e-3f,
              p3c = 4.1665795894e-2f, p4c = 1.6666665459e-1f, p5c = 5.0000001201e-1f;
  float xc = fminf(fmaxf(x, -87.33654785f), 88.72283935f);
  float m = floorf(__fmaf_rn(xc, LOG2EF, 0.5f));
  float r = __fmaf_rn(m, -ln2_hi, xc);
  r = __fmaf_rn(m, nln2_lo, r);
  float r2 = __fmul_rn(r, r);
  float y = p0;
  y = __fmaf_rn(y, r, p1c);
  y = __fmaf_rn(y, r, p2c);
  y = __fmaf_rn(y, r, p3c);
  y = __fmaf_rn(y, r, p4c);
  y = __fmaf_rn(y, r, p5c);
  y = __fmaf_rn(y, r2, r);
  y = __fadd_rn(y, 1.0f);
  int n = (int)m;
  float s2 = __uint_as_float((uint32_t)(n + 127) << 23);  // exact 2^n (n in normal range here)
  return __fmul_rn(y, s2);
}

// XLA LogisticExpander (current): logistic(x) = 1 / (1 + exp(-x))
__device__ __forceinline__ float sigmoid_exp(float x) {
  float e = xla_expf(-x);
  return __fdiv_rn(1.0f, __fadd_rn(1.0f, e));
}

__device__ __forceinline__ unsigned long long pack_key(float s, int idx) {
  // ascending sort == (s desc, idx asc); s in (0,1): positive floats bit-ordered
  return ((unsigned long long)(__float_as_uint(s) ^ 0xFFFFFFFFu) << 32) | (uint32_t)idx;
}

// ---------------- masks: 1.0 = DROPPED (u < 0.1) ----------------
__global__ void mask_kernel(uint32_t fk0a, uint32_t fk1a, uint32_t fk0b, uint32_t fk1b,
                            float* __restrict__ mask1, float* __restrict__ mask2) {
  int i = blockIdx.x * blockDim.x + threadIdx.x;
  if (i >= Nn * NHn) return;
  uint32_t x0 = 0u, x1 = (uint32_t)i;
  tf2x32(fk0a, fk1a, x0, x1);
  uint32_t bits = x0 ^ x1;
  float u = __uint_as_float((bits >> 9) | 0x3f800000u) - 1.0f;
  mask1[i] = (u < 0.1f) ? 1.0f : 0.0f;
  x0 = 0u; x1 = (uint32_t)i;
  tf2x32(fk0b, fk1b, x0, x1);
  bits = x0 ^ x1;
  u = __uint_as_float((bits >> 9) | 0x3f800000u) - 1.0f;
  mask2[i] = (u < 0.1f) ? 1.0f : 0.0f;
}

// ---------------- dropout: p = where(m, 0, pos), float4 ----------------
__global__ void drop_kernel(const float4* __restrict__ pos1, const float4* __restrict__ pos2,
                            const float4* __restrict__ mask1, const float4* __restrict__ mask2,
                            float4* __restrict__ p1, float4* __restrict__ p2) {
  size_t i4 = (size_t)blockIdx.x * blockDim.x + threadIdx.x;  // grid covers B*N*NH/4
  int nh4 = (int)(i4 & (size_t)(Nn * NHn / 4 - 1));
  float4 m1 = mask1[nh4], m2 = mask2[nh4];
  float4 a = pos1[i4], c = pos2[i4];
  float4 o1, o2;
  o1.x = (m1.x != 0.0f) ? 0.0f : a.x;  o1.y = (m1.y != 0.0f) ? 0.0f : a.y;
  o1.z = (m1.z != 0.0f) ? 0.0f : a.z;  o1.w = (m1.w != 0.0f) ? 0.0f : a.w;
  o2.x = (m2.x != 0.0f) ? 0.0f : c.x;  o2.y = (m2.y != 0.0f) ? 0.0f : c.y;
  o2.z = (m2.z != 0.0f) ? 0.0f : c.z;  o2.w = (m2.w != 0.0f) ? 0.0f : c.w;
  p1[i4] = o1;
  p2[i4] = o2;
}

// ------- g = sigmoid(mean axis=1): LDS-staged, chain order n-ascending (bit-exact) -----
__global__ __launch_bounds__(256) void gmean_kernel(const float* __restrict__ p1,
                                                    const float* __restrict__ p2,
                                                    float* __restrict__ g1,
                                                    float* __restrict__ g2) {
  __shared__ __align__(16) float s1[32][64], s2[32][64];
  int b = blockIdx.x, t = threadIdx.x;
  const float* P1 = p1 + (size_t)b * Nn * NHn;
  const float* P2 = p2 + (size_t)b * Nn * NHn;
  float a1 = 0.0f, a2 = 0.0f;
  for (int c = 0; c < Nn / 32; ++c) {
    __syncthreads();
    // load 32 rows (32*64 = 2048 floats = 512 float4 per array; 2 f4/thread each)
#pragma unroll
    for (int ppp = 0; ppp < 2; ++ppp) {
      int f = ppp * 256 + t;         // 0..511
      int row = f >> 4, c4 = f & 15;
      *(float4*)&s1[row][c4 * 4] = *(const float4*)&P1[(size_t)(c * 32 + row) * NHn + c4 * 4];
      *(float4*)&s2[row][c4 * 4] = *(const float4*)&P2[(size_t)(c * 32 + row) * NHn + c4 * 4];
    }
    __syncthreads();
    if (t < 64) {
#pragma unroll
      for (int u = 0; u < 32; ++u) {
        a1 = __fadd_rn(a1, s1[u][t]);
        a2 = __fadd_rn(a2, s2[u][t]);
      }
    }
  }
  if (t < 64) {
    float m1 = __fdiv_rn(a1, 2048.0f);  // exact pow2
    float m2 = __fdiv_rn(a2, 2048.0f);
    g1[b * 64 + t] = sigmoid_exp(m1);
    g2[b * 64 + t] = sigmoid_exp(m2);
  }
}

// -------- cascade-1 v2: dedup (2 threads/row), W via wave-uniform global (s_load) ------
__global__ __launch_bounds__(256, 2) void logits1_np(
    const float* __restrict__ p1, const float* __restrict__ p2,
    const float* __restrict__ neg1, const float* __restrict__ neg2,
    const float* __restrict__ mask1, const float* __restrict__ mask2,
    const float* __restrict__ g1, const float* __restrict__ g2,
    const float* __restrict__ W0, const float* __restrict__ b0p,
    const float* __restrict__ alphap,
    float* __restrict__ out0, unsigned long long* __restrict__ key1) {
  __shared__ __align__(16) float xp[128][68], xn[128][68];
  int b = blockIdx.y, n0 = blockIdx.x * 128, t = threadIdx.x;
  for (int c = 0; c < 32; ++c) {
    int idx = c * 256 + t, row = idx >> 6, i = idx & 63;
    size_t ga = ((size_t)b * Nn + n0 + row) * NHn + i;
    int ma = (n0 + row) * NHn + i;
    xp[row][i] = __fmul_rn(__fadd_rn(p1[ga], p2[ga]), 0.5f);
    float nv1 = (mask1[ma] != 0.0f) ? 0.0f : neg1[ga];
    float nv2 = (mask2[ma] != 0.0f) ? 0.0f : neg2[ga];
    xn[row][i] = __fmul_rn(__fadd_rn(nv1, nv2), 0.5f);
  }
  __syncthreads();
  int row = t >> 1, e = t & 1;               // e=0: pos side, e=1: neg side
  const float* x = e ? &xn[row][0] : &xp[row][0];
  // stage 1: T = x @ W0 (i-ascending FMA chain per j; W0 wave-uniform -> s_load)
  float T[64];
#pragma unroll
  for (int j = 0; j < 64; ++j) T[j] = 0.0f;
  for (int i = 0; i < 64; ++i) {
    float xv = x[i];
#pragma unroll
    for (int jb = 0; jb < 16; ++jb) {
      float4 wv = *(const float4*)&W0[i * 64 + jb * 4];
      T[jb * 4 + 0] = __fmaf_rn(xv, wv.x, T[jb * 4 + 0]);
      T[jb * 4 + 1] = __fmaf_rn(xv, wv.y, T[jb * 4 + 1]);
      T[jb * 4 + 2] = __fmaf_rn(xv, wv.z, T[jb * 4 + 2]);
      T[jb * 4 + 3] = __fmaf_rn(xv, wv.w, T[jb * 4 + 3]);
    }
  }
  // stage 2: sequential scalar j (separate mul/add) against g1 and g2 (wave-uniform)
  const float* G1 = g1 + b * 64;
  const float* G2 = g2 + b * 64;
  float acc1 = 0.0f, acc2 = 0.0f;
#pragma unroll
  for (int jb = 0; jb < 16; ++jb) {
    float4 gv1 = *(const float4*)&G1[jb * 4];
    float4 gv2 = *(const float4*)&G2[jb * 4];
    acc1 = __fadd_rn(acc1, __fmul_rn(T[jb * 4 + 0], gv1.x));
    acc1 = __fadd_rn(acc1, __fmul_rn(T[jb * 4 + 1], gv1.y));
    acc1 = __fadd_rn(acc1, __fmul_rn(T[jb * 4 + 2], gv1.z));
    acc1 = __fadd_rn(acc1, __fmul_rn(T[jb * 4 + 3], gv1.w));
    acc2 = __fadd_rn(acc2, __fmul_rn(T[jb * 4 + 0], gv2.x));
    acc2 = __fadd_rn(acc2, __fmul_rn(T[jb * 4 + 1], gv2.y));
    acc2 = __fadd_rn(acc2, __fmul_rn(T[jb * 4 + 2], gv2.z));
    acc2 = __fadd_rn(acc2, __fmul_rn(T[jb * 4 + 3], gv2.w));
  }
  float b0 = *b0p, al = *alphap, om = __fsub_rn(1.0f, al);
  float L = __fadd_rn(__fmul_rn(al, __fadd_rn(acc1, b0)),
                      __fmul_rn(om, __fadd_rn(acc2, b0)));
  float Lother = __shfl_xor(L, 1);           // e=0 gets Ln, e=1 gets Lp
  int n = n0 + row;
  if (e == 0) {
    out0[(size_t)b * (2 * Nn) + n] = L;
    float d = __fsub_rn(Lother, L);          // ln - lp
    key1[(size_t)b * Nn + n] = pack_key(sigmoid_exp(d), n);
  } else {
    out0[(size_t)b * (2 * Nn) + Nn + n] = L;
  }
}

// ------- top-k: ascending bitonic sort of packed u64 keys (verified ≡ brute-force) -----
template <int S>
__global__ void topk_bitonic(const unsigned long long* __restrict__ keysrc,
                             int* __restrict__ idx_out) {
  constexpr int K = S / 2;
  __shared__ unsigned long long keys[S];
  int b = blockIdx.x;
  for (int i = threadIdx.x; i < S; i += blockDim.x)
    keys[i] = keysrc[(size_t)b * S + i];
  for (int k = 2; k <= S; k <<= 1) {
    for (int j = k >> 1; j > 0; j >>= 1) {
      __syncthreads();
      for (int t = threadIdx.x; t < S / 2; t += blockDim.x) {
        int i = ((t / j) * (j << 1)) + (t % j);
        unsigned long long a = keys[i], c = keys[i + j];
        if (((i & k) == 0) == (a > c)) { keys[i] = c; keys[i + j] = a; }
      }
    }
  }
  __syncthreads();
  for (int t = threadIdx.x; t < K; t += blockDim.x)
    idx_out[(size_t)b * K + t] = (int)(keys[t] & 0xffffffffu);
}

// ---------------- per-column sort across batch (jnp.sort axis=0) ----------------
__global__ void colsort_kernel(const int* __restrict__ idx, int* __restrict__ sidx, int K) {
  int j = blockIdx.x * blockDim.x + threadIdx.x;
  if (j >= K) return;
  int v[16];
  for (int b = 0; b < 16; ++b) v[b] = idx[b * K + j];
  for (int a = 1; a < 16; ++a) {
    int x = v[a]; int c = a - 1;
    while (c >= 0 && v[c] > x) { v[c + 1] = v[c]; --c; }
    v[c + 1] = x;
  }
  for (int b = 0; b < 16; ++b) sidx[b * K + j] = v[b];
}

// ------- selected-row matmul v4: bit-exact m-ascending FMA chains, 4x4 micro-tile ------
// 64 rows/block, m-tile 128; 8 LDS instr / 64 FMA -> FMA-bound.
__global__ __launch_bounds__(256) void selmm_np4(const float* __restrict__ M,
                                                 const float* __restrict__ P,
                                                 const int* __restrict__ sidx,
                                                 float* __restrict__ L) {
  __shared__ __align__(16) float ash[64][132];
  __shared__ __align__(16) float psh[128][64];
  __shared__ int rj[64];
  int b = blockIdx.y, j0 = blockIdx.x * 64, t = threadIdx.x;
  if (t < 64) rj[t] = sidx[b * K1 + j0 + t];
  __syncthreads();
  int cg = t & 15, rg = t >> 4;      // 16 col-groups x 16 row-groups (4 rows each)
  const float* Mb = M + (size_t)b * Nn * Nn;
  const float* Pb = P + (size_t)b * Nn * NHn;
  float acc[4][4];
#pragma unroll
  for (int r = 0; r < 4; ++r)
#pragma unroll
    for (int c = 0; c < 4; ++c) acc[r][c] = 0.0f;

  for (int m0 = 0; m0 < Nn; m0 += 128) {
    // stage A rows: 64 rows x 128 cols = 2048 float4 / 256 threads = 8 each
#pragma unroll
    for (int pass = 0; pass < 8; ++pass) {
      int f = pass * 256 + t;
      int row = f >> 5, c4 = f & 31;
      *(float4*)&ash[row][c4 * 4] = *(const float4*)&Mb[(size_t)rj[row] * Nn + m0 + c4 * 4];
    }
    // stage P: 128 x 64 = 2048 float4 / 256 = 8 each
#pragma unroll
    for (int pass = 0; pass < 8; ++pass) {
      int f = pass * 256 + t;
      int mm = f >> 4, c4 = f & 15;
      *(float4*)&psh[mm][c4 * 4] = *(const float4*)&Pb[(size_t)(m0 + mm) * NHn + c4 * 4];
    }
    __syncthreads();
#pragma unroll 4
    for (int mb = 0; mb < 32; ++mb) {
      float4 a0 = *(const float4*)&ash[rg * 4 + 0][mb * 4];
      float4 a1 = *(const float4*)&ash[rg * 4 + 1][mb * 4];
      float4 a2 = *(const float4*)&ash[rg * 4 + 2][mb * 4];
      float4 a3 = *(const float4*)&ash[rg * 4 + 3][mb * 4];
      float4 pv0 = *(const float4*)&psh[mb * 4 + 0][cg * 4];
      float4 pv1 = *(const float4*)&psh[mb * 4 + 1][cg * 4];
      float4 pv2 = *(const float4*)&psh[mb * 4 + 2][cg * 4];
      float4 pv3 = *(const float4*)&psh[mb * 4 + 3][cg * 4];
      // m ascending per accumulator chain (bit-exact)
#define STEP(q, aq, pq)                                        \
      acc[0][0] = __fmaf_rn(a0.aq, pq.x, acc[0][0]);           \
      acc[0][1] = __fmaf_rn(a0.aq, pq.y, acc[0][1]);           \
      acc[0][2] = __fmaf_rn(a0.aq, pq.z, acc[0][2]);           \
      acc[0][3] = __fmaf_rn(a0.aq, pq.w, acc[0][3]);           \
      acc[1][0] = __fmaf_rn(a1.aq, pq.x, acc[1][0]);           \
      acc[1][1] = __fmaf_rn(a1.aq, pq.y, acc[1][1]);           \
      acc[1][2] = __fmaf_rn(a1.aq, pq.z, acc[1][2]);           \
      acc[1][3] = __fmaf_rn(a1.aq, pq.w, acc[1][3]);           \
      acc[2][0] = __fmaf_rn(a2.aq, pq.x, acc[2][0]);           \
      acc[2][1] = __fmaf_rn(a2.aq, pq.y, acc[2][1]);           \
      acc[2][2] = __fmaf_rn(a2.aq, pq.z, acc[2][2]);           \
      acc[2][3] = __fmaf_rn(a2.aq, pq.w, acc[2][3]);           \
      acc[3][0] = __fmaf_rn(a3.aq, pq.x, acc[3][0]);           \
      acc[3][1] = __fmaf_rn(a3.aq, pq.y, acc[3][1]);           \
      acc[3][2] = __fmaf_rn(a3.aq, pq.z, acc[3][2]);           \
      acc[3][3] = __fmaf_rn(a3.aq, pq.w, acc[3][3]);
      STEP(0, x, pv0)
      STEP(1, y, pv1)
      STEP(2, z, pv2)
      STEP(3, w, pv3)
#undef STEP
    }
    __syncthreads();
  }
#pragma unroll
  for (int r = 0; r < 4; ++r) {
    size_t base = ((size_t)b * K1 + j0 + rg * 4 + r) * NHn + cg * 4;
    L[base + 0] = sigmoid_exp(acc[r][0]);
    L[base + 1] = sigmoid_exp(acc[r][1]);
    L[base + 2] = sigmoid_exp(acc[r][2]);
    L[base + 3] = sigmoid_exp(acc[r][3]);
  }
}

// -------- cascade-2 v2: dedup (2 threads/row), W via wave-uniform global (s_load) ------
__global__ __launch_bounds__(256, 2) void logits2_np(
    const float* __restrict__ p1, const float* __restrict__ p2,
    const float* __restrict__ neg1, const float* __restrict__ neg2,
    const float* __restrict__ mask1, const float* __restrict__ mask2,
    const int* __restrict__ sidx1,
    const float* __restrict__ l1, const float* __restrict__ l2,
    const float* __restrict__ W1, const float* __restrict__ b1p,
    const float* __restrict__ betap,
    float* __restrict__ out1, unsigned long long* __restrict__ key2) {
  __shared__ __align__(16) float xp[128][68], xn[128][68];
  __shared__ int rrs[128];
  int b = blockIdx.y, j0 = blockIdx.x * 128, t = threadIdx.x;
  if (t < 128) rrs[t] = sidx1[b * K1 + j0 + t];
  __syncthreads();
  for (int c = 0; c < 32; ++c) {
    int idx = c * 256 + t, row = idx >> 6, i = idx & 63;
    int rr = rrs[row];
    size_t ga = ((size_t)b * Nn + rr) * NHn + i;
    int ma = rr * NHn + i;
    xp[row][i] = __fmul_rn(__fadd_rn(p1[ga], p2[ga]), 0.5f);
    float nv1 = (mask1[ma] != 0.0f) ? 0.0f : neg1[ga];
    float nv2 = (mask2[ma] != 0.0f) ? 0.0f : neg2[ga];
    xn[row][i] = __fmul_rn(__fadd_rn(nv1, nv2), 0.5f);
  }
  __syncthreads();
  int row = t >> 1, e = t & 1;
  const float* x = e ? &xn[row][0] : &xp[row][0];
  float T[64];
#pragma unroll
  for (int j = 0; j < 64; ++j) T[j] = 0.0f;
  for (int i = 0; i < 64; ++i) {
    float xv = x[i];
#pragma unroll
    for (int jb = 0; jb < 16; ++jb) {
      float4 wv = *(const float4*)&W1[i * 64 + jb * 4];
      T[jb * 4 + 0] = __fmaf_rn(xv, wv.x, T[jb * 4 + 0]);
      T[jb * 4 + 1] = __fmaf_rn(xv, wv.y, T[jb * 4 + 1]);
      T[jb * 4 + 2] = __fmaf_rn(xv, wv.z, T[jb * 4 + 2]);
      T[jb * 4 + 3] = __fmaf_rn(xv, wv.w, T[jb * 4 + 3]);
    }
  }
  // stage 2: sequential scalar dots against y1 (l1 row) and y2 (l2 row)
  const float* Y1 = l1 + ((size_t)b * K1 + j0 + row) * NHn;
  const float* Y2 = l2 + ((size_t)b * K1 + j0 + row) * NHn;
  float acc1 = 0.0f, acc2 = 0.0f;
#pragma unroll
  for (int jb = 0; jb < 16; ++jb) {
    float4 yv1 = *(const float4*)&Y1[jb * 4];
    float4 yv2 = *(const float4*)&Y2[jb * 4];
    acc1 = __fadd_rn(acc1, __fmul_rn(T[jb * 4 + 0], yv1.x));
    acc1 = __fadd_rn(acc1, __fmul_rn(T[jb * 4 + 1], yv1.y));
    acc1 = __fadd_rn(acc1, __fmul_rn(T[jb * 4 + 2], yv1.z));
    acc1 = __fadd_rn(acc1, __fmul_rn(T[jb * 4 + 3], yv1.w));
    acc2 = __fadd_rn(acc2, __fmul_rn(T[jb * 4 + 0], yv2.x));
    acc2 = __fadd_rn(acc2, __fmul_rn(T[jb * 4 + 1], yv2.y));
    acc2 = __fadd_rn(acc2, __fmul_rn(T[jb * 4 + 2], yv2.z));
    acc2 = __fadd_rn(acc2, __fmul_rn(T[jb * 4 + 3], yv2.w));
  }
  float bb = *b1p, be = *betap, om = __fsub_rn(1.0f, be);
  float L = __fadd_rn(__fmul_rn(be, __fadd_rn(acc1, bb)),
                      __fmul_rn(om, __fadd_rn(acc2, bb)));
  float Lother = __shfl_xor(L, 1);
  int j = j0 + row;
  if (e == 0) {
    out1[(size_t)b * (2 * K1) + j] = L;
    float d = __fsub_rn(Lother, L);
    key2[(size_t)b * K1 + j] = pack_key(sigmoid_exp(d), j);
  } else {
    out1[(size_t)b * (2 * K1) + K1 + j] = L;
  }
}

// ---------------- cascade-3 logits (values only; 0.2587 slack) ----------------
__global__ void logits3_kernel(const float* __restrict__ p1, const float* __restrict__ p2,
                               const float* __restrict__ neg1, const float* __restrict__ neg2,
                               const float* __restrict__ mask1, const float* __restrict__ mask2,
                               const int* __restrict__ sidx1, const int* __restrict__ sidx2,
                               const float* __restrict__ W2,
                               const float* __restrict__ b2p, const float* __restrict__ lamp,
                               float* __restrict__ out2) {
  int b = blockIdx.y, tt = blockIdx.x, h = threadIdx.x;  // 64 threads
  int rr = sidx1[b * K1 + sidx2[b * K2 + tt]];
  __shared__ float XP[64], XN[64];
  size_t xb = ((size_t)b * Nn + rr) * NHn + h;
  int ma = rr * NHn + h;
  float pv1 = p1[xb], pv2 = p2[xb];
  float nv1 = (mask1[ma] != 0.0f) ? 0.0f : neg1[xb];
  float nv2 = (mask2[ma] != 0.0f) ? 0.0f : neg2[xb];
  XP[h] = (pv1 + pv2) * 0.5f;
  XN[h] = (nv1 + nv2) * 0.5f;
  __syncthreads();
  float tp = 0.f, tn = 0.f;
#pragma unroll 8
  for (int i = 0; i < 64; ++i) {
    float ww = W2[i * 64 + h];
    tp = fmaf(XP[i], ww, tp);
    tn = fmaf(XN[i], ww, tn);
  }
  float y1 = sigmoid_exp(pv1);
  float y2 = sigmoid_exp(pv2);
  float p11 = tp * y1, p12 = tp * y2, p21 = tn * y1, p22 = tn * y2;
  for (int o = 32; o > 0; o >>= 1) {
    p11 += __shfl_down(p11, o);
    p12 += __shfl_down(p12, o);
    p21 += __shfl_down(p21, o);
    p22 += __shfl_down(p22, o);
  }
  if (h == 0) {
    float bb = *b2p, lm = *lamp;
    out2[(size_t)b * (2 * K2) + tt]      = lm * (p11 + bb) + (1.0f - lm) * (p12 + bb);
    out2[(size_t)b * (2 * K2) + K2 + tt] = lm * (p21 + bb) + (1.0f - lm) * (p22 + bb);
  }
}

// ---------------- host ----------------
extern "C" void kernel_launch(void* const* d_in, const int* in_sizes, int n_in,
                              void* d_out, int out_size, void* d_ws, size_t ws_size,
                              hipStream_t stream) {
  (void)in_sizes; (void)n_in; (void)out_size; (void)ws_size;

  const float* adj   = (const float*)d_in[0];
  const float* diff  = (const float*)d_in[1];
  const float* pos1  = (const float*)d_in[2];
  const float* pos2  = (const float*)d_in[3];
  const float* neg1  = (const float*)d_in[4];
  const float* neg2  = (const float*)d_in[5];
  const float* W0    = (const float*)d_in[6];
  const float* b0    = (const float*)d_in[7];
  const float* W1    = (const float*)d_in[8];
  const float* b1    = (const float*)d_in[9];
  const float* W2    = (const float*)d_in[10];
  const float* b2    = (const float*)d_in[11];
  const float* alpha = (const float*)d_in[12];
  const float* beta  = (const float*)d_in[13];
  const float* lamda = (const float*)d_in[14];

  float* out0 = (float*)d_out;           // [16, 4096]
  float* out1 = out0 + Bn * 2 * Nn;      // [16, 2048]
  float* out2 = out1 + Bn * 2 * K1;      // [16, 1024]

  char* w = (char*)d_ws;
  size_t off = 0;
  auto alloc = [&](size_t bytes) -> void* {
    void* p = w + off;
    off += (bytes + 255) & ~(size_t)255;
    return p;
  };
  float* mask1 = (float*)alloc((size_t)Nn * NHn * 4);
  float* mask2 = (float*)alloc((size_t)Nn * NHn * 4);
  float* p1    = (float*)alloc((size_t)Bn * Nn * NHn * 4);
  float* p2    = (float*)alloc((size_t)Bn * Nn * NHn * 4);
  float* g1    = (float*)alloc((size_t)Bn * 64 * 4);
  float* g2    = (float*)alloc((size_t)Bn * 64 * 4);
  unsigned long long* key1 = (unsigned long long*)alloc((size_t)Bn * Nn * 8);
  unsigned long long* key2 = (unsigned long long*)alloc((size_t)Bn * K1 * 8);
  int*   idx1  = (int*)alloc((size_t)Bn * K1 * 4);
  int*   sidx1 = (int*)alloc((size_t)Bn * K1 * 4);
  int*   idx2  = (int*)alloc((size_t)Bn * K2 * 4);
  int*   sidx2 = (int*)alloc((size_t)Bn * K2 * 4);
  float* l1    = (float*)alloc((size_t)Bn * K1 * NHn * 4);
  float* l2    = (float*)alloc((size_t)Bn * K1 * NHn * 4);

  uint32_t fk0a = 0u, fk1a = 0u;
  { uint32_t x0 = 0u, x1 = 0u; tf2x32(0u, 1u, x0, x1); fk0a = x0; fk1a = x1; }
  uint32_t fk0b = 0u, fk1b = 0u;
  { uint32_t x0 = 0u, x1 = 1u; tf2x32(0u, 1u, x0, x1); fk0b = x0; fk1b = x1; }

  mask_kernel<<<(Nn * NHn + 255) / 256, 256, 0, stream>>>(fk0a, fk1a, fk0b, fk1b, mask1, mask2);

  drop_kernel<<<(Bn * Nn * NHn / 4) / 256, 256, 0, stream>>>(
      (const float4*)pos1, (const float4*)pos2, (const float4*)mask1, (const float4*)mask2,
      (float4*)p1, (float4*)p2);

  gmean_kernel<<<Bn, 256, 0, stream>>>(p1, p2, g1, g2);

  logits1_np<<<dim3(Nn / 128, Bn), 256, 0, stream>>>(p1, p2, neg1, neg2, mask1, mask2,
                                                     g1, g2, W0, b0, alpha, out0, key1);

  topk_bitonic<2048><<<Bn, 1024, 0, stream>>>(key1, idx1);
  colsort_kernel<<<K1 / 256, 256, 0, stream>>>(idx1, sidx1, K1);

  selmm_np4<<<dim3(K1 / 64, Bn), 256, 0, stream>>>(adj, p1, sidx1, l1);
  selmm_np4<<<dim3(K1 / 64, Bn), 256, 0, stream>>>(diff, p2, sidx1, l2);

  logits2_np<<<dim3(K1 / 128, Bn), 256, 0, stream>>>(p1, p2, neg1, neg2, mask1, mask2,
                                                     sidx1, l1, l2, W1, b1, beta, out1, key2);

  topk_bitonic<1024><<<Bn, 512, 0, stream>>>(key2, idx2);
  colsort_kernel<<<K2 / 256, 256, 0, stream>>>(idx2, sidx2, K2);

  logits3_kernel<<<dim3(K2, Bn), 64, 0, stream>>>(p1, p2, neg1, neg2, mask1, mask2,
                                                  sidx1, sidx2, W2, b2, lamda, out2);
}

// Round 16
// 338.015 us; speedup vs baseline: 1.1778x; 1.1778x over previous
//
#include <hip/hip_runtime.h>
#include <cstdint>
#include <cstddef>

static constexpr int Bn  = 16;
static constexpr int Nn  = 2048;
static constexpr int NHn = 64;
static constexpr int K1  = 1024;
static constexpr int K2  = 512;

// ---------------- threefry2x32 (exact JAX semantics; verified via out0) ----------------
__host__ __device__ inline void tf2x32(uint32_t k0, uint32_t k1, uint32_t& x0, uint32_t& x1) {
  const uint32_t ks0 = k0, ks1 = k1, ks2 = k0 ^ k1 ^ 0x1BD11BDAu;
  x0 += ks0; x1 += ks1;
  const int R[20] = {13,15,26,6, 17,29,16,24, 13,15,26,6, 17,29,16,24, 13,15,26,6};
  const uint32_t ks[3] = {ks0, ks1, ks2};
  int inj = 0;
  for (int r = 0; r < 20; ++r) {
    x0 += x1;
    x1 = (x1 << R[r]) | (x1 >> (32 - R[r]));
    x1 ^= x0;
    if ((r & 3) == 3) {
      ++inj;
      x0 += ks[inj % 3];
      x1 += ks[(inj + 1) % 3] + (uint32_t)inj;
    }
  }
}

// ---------------- XLA CPU f32 exp (GenerateVF32Exp / Eigen pexp, Cephes, FMA) ----------
__device__ __forceinline__ float xla_expf(float x) {
  const float LOG2EF   = 1.44269504088896341f;
  const float ln2_hi   = 0.693359375f;
  const float nln2_lo  = 2.12194440e-4f;     // -(ln2 - ln2_hi)
  const float p0 = 1.9875691500e-4f, p1c = 1.3981999507e-3f, p2c = 8.3334519073e-3f,
              p3c = 4.1665795894e-2f, p4c = 1.6666665459e-1f, p5c = 5.0000001201e-1f;
  float xc = fminf(fmaxf(x, -87.33654785f), 88.72283935f);
  float m = floorf(__fmaf_rn(xc, LOG2EF, 0.5f));
  float r = __fmaf_rn(m, -ln2_hi, xc);
  r = __fmaf_rn(m, nln2_lo, r);
  float r2 = __fmul_rn(r, r);
  float y = p0;
  y = __fmaf_rn(y, r, p1c);
  y = __fmaf_rn(y, r, p2c);
  y = __fmaf_rn(y, r, p3c);
  y = __fmaf_rn(y, r, p4c);
  y = __fmaf_rn(y, r, p5c);
  y = __fmaf_rn(y, r2, r);
  y = __fadd_rn(y, 1.0f);
  int n = (int)m;
  float s2 = __uint_as_float((uint32_t)(n + 127) << 23);  // exact 2^n (n in normal range here)
  return __fmul_rn(y, s2);
}

// XLA LogisticExpander (current): logistic(x) = 1 / (1 + exp(-x))
__device__ __forceinline__ float sigmoid_exp(float x) {
  float e = xla_expf(-x);
  return __fdiv_rn(1.0f, __fadd_rn(1.0f, e));
}

__device__ __forceinline__ unsigned long long pack_key(float s, int idx) {
  // ascending sort == (s desc, idx asc); s in (0,1): positive floats bit-ordered
  return ((unsigned long long)(__float_as_uint(s) ^ 0xFFFFFFFFu) << 32) | (uint32_t)idx;
}

// ---------------- masks: 1.0 = DROPPED (u < 0.1) ----------------
__global__ void mask_kernel(uint32_t fk0a, uint32_t fk1a, uint32_t fk0b, uint32_t fk1b,
                            float* __restrict__ mask1, float* __restrict__ mask2) {
  int i = blockIdx.x * blockDim.x + threadIdx.x;
  if (i >= Nn * NHn) return;
  uint32_t x0 = 0u, x1 = (uint32_t)i;
  tf2x32(fk0a, fk1a, x0, x1);
  uint32_t bits = x0 ^ x1;
  float u = __uint_as_float((bits >> 9) | 0x3f800000u) - 1.0f;
  mask1[i] = (u < 0.1f) ? 1.0f : 0.0f;
  x0 = 0u; x1 = (uint32_t)i;
  tf2x32(fk0b, fk1b, x0, x1);
  bits = x0 ^ x1;
  u = __uint_as_float((bits >> 9) | 0x3f800000u) - 1.0f;
  mask2[i] = (u < 0.1f) ? 1.0f : 0.0f;
}

// ---------------- dropout: p = where(m, 0, pos), float4 ----------------
__global__ void drop_kernel(const float4* __restrict__ pos1, const float4* __restrict__ pos2,
                            const float4* __restrict__ mask1, const float4* __restrict__ mask2,
                            float4* __restrict__ p1, float4* __restrict__ p2) {
  size_t i4 = (size_t)blockIdx.x * blockDim.x + threadIdx.x;  // grid covers B*N*NH/4
  int nh4 = (int)(i4 & (size_t)(Nn * NHn / 4 - 1));
  float4 m1 = mask1[nh4], m2 = mask2[nh4];
  float4 a = pos1[i4], c = pos2[i4];
  float4 o1, o2;
  o1.x = (m1.x != 0.0f) ? 0.0f : a.x;  o1.y = (m1.y != 0.0f) ? 0.0f : a.y;
  o1.z = (m1.z != 0.0f) ? 0.0f : a.z;  o1.w = (m1.w != 0.0f) ? 0.0f : a.w;
  o2.x = (m2.x != 0.0f) ? 0.0f : c.x;  o2.y = (m2.y != 0.0f) ? 0.0f : c.y;
  o2.z = (m2.z != 0.0f) ? 0.0f : c.z;  o2.w = (m2.w != 0.0f) ? 0.0f : c.w;
  p1[i4] = o1;
  p2[i4] = o2;
}

// ---------------- g = sigmoid(mean axis=1): sequential-n f32 reduce, then /2048 --------
__global__ void gmean_kernel(const float* __restrict__ p1, const float* __restrict__ p2,
                             float* __restrict__ g1, float* __restrict__ g2) {
  int b = blockIdx.x, h = threadIdx.x;  // 64 threads
  const float* P1 = p1 + (size_t)b * Nn * NHn + h;
  const float* P2 = p2 + (size_t)b * Nn * NHn + h;
  float a1 = 0.0f, a2 = 0.0f;
  for (int n = 0; n < Nn; n += 8) {
    float v1[8], v2[8];
#pragma unroll
    for (int u = 0; u < 8; ++u) {
      v1[u] = P1[(size_t)(n + u) * NHn];
      v2[u] = P2[(size_t)(n + u) * NHn];
    }
#pragma unroll
    for (int u = 0; u < 8; ++u) {
      a1 = __fadd_rn(a1, v1[u]);
      a2 = __fadd_rn(a2, v2[u]);
    }
  }
  float m1 = __fdiv_rn(a1, 2048.0f);  // exact pow2
  float m2 = __fdiv_rn(a2, 2048.0f);
  g1[b * 64 + h] = sigmoid_exp(m1);
  g2[b * 64 + h] = sigmoid_exp(m2);
}

// -------- cascade-1: Eigen-FMA stage1 (float4 w from LDS) + sequential mul/add stage2 --
__global__ __launch_bounds__(256) void logits1_np(
    const float* __restrict__ p1, const float* __restrict__ p2,
    const float* __restrict__ neg1, const float* __restrict__ neg2,
    const float* __restrict__ mask1, const float* __restrict__ mask2,
    const float* __restrict__ g1, const float* __restrict__ g2,
    const float* __restrict__ W0, const float* __restrict__ b0p,
    const float* __restrict__ alphap,
    float* __restrict__ out0, unsigned long long* __restrict__ key1) {
  __shared__ __align__(16) float xp[64][68], xn[64][68], w[4096], g[2][64];
  int b = blockIdx.y, n0 = blockIdx.x * 64, t = threadIdx.x;
  for (int c = 0; c < 16; ++c) {
    int idx = c * 256 + t, row = idx >> 6, i = idx & 63;
    size_t ga = ((size_t)b * Nn + n0 + row) * NHn + i;
    int ma = (n0 + row) * NHn + i;
    xp[row][i] = __fmul_rn(__fadd_rn(p1[ga], p2[ga]), 0.5f);
    float nv1 = (mask1[ma] != 0.0f) ? 0.0f : neg1[ga];
    float nv2 = (mask2[ma] != 0.0f) ? 0.0f : neg2[ga];
    xn[row][i] = __fmul_rn(__fadd_rn(nv1, nv2), 0.5f);
    w[idx] = W0[idx];
  }
  if (t < 64) { g[0][t] = g1[b * 64 + t]; g[1][t] = g2[b * 64 + t]; }
  __syncthreads();
  int row = t >> 2, e = t & 3;
  const float* x = (e & 2) ? &xn[row][0] : &xp[row][0];
  const float* gg = g[e & 1];
  // stage 1: T = x @ W0  (per-entry sequential i-ascending FMA chain; j chains indep.)
  float T[64];
#pragma unroll
  for (int j = 0; j < 64; ++j) T[j] = 0.0f;
  for (int i = 0; i < 64; ++i) {
    float xv = x[i];
#pragma unroll
    for (int jb = 0; jb < 16; ++jb) {
      float4 wv = *(const float4*)&w[i * 64 + jb * 4];
      T[jb * 4 + 0] = __fmaf_rn(xv, wv.x, T[jb * 4 + 0]);
      T[jb * 4 + 1] = __fmaf_rn(xv, wv.y, T[jb * 4 + 1]);
      T[jb * 4 + 2] = __fmaf_rn(xv, wv.z, T[jb * 4 + 2]);
      T[jb * 4 + 3] = __fmaf_rn(xv, wv.w, T[jb * 4 + 3]);
    }
  }
  // stage 2: sequential scalar j loop (separate mul/add), g read as float4 into regs
  float acc = 0.0f;
#pragma unroll
  for (int jb = 0; jb < 16; ++jb) {
    float4 gv = *(const float4*)&gg[jb * 4];
    acc = __fadd_rn(acc, __fmul_rn(T[jb * 4 + 0], gv.x));
    acc = __fadd_rn(acc, __fmul_rn(T[jb * 4 + 1], gv.y));
    acc = __fadd_rn(acc, __fmul_rn(T[jb * 4 + 2], gv.z));
    acc = __fadd_rn(acc, __fmul_rn(T[jb * 4 + 3], gv.w));
  }
  float a = __fadd_rn(acc, *b0p);
  float al = *alphap, om = __fsub_rn(1.0f, al);
  float other = __shfl_xor(a, 1);
  float L = __fadd_rn(__fmul_rn(al, a), __fmul_rn(om, other));
  float Lneg = __shfl_xor(L, 2);
  int n = n0 + row;
  if (e == 0) {
    out0[(size_t)b * (2 * Nn) + n] = L;
    float d = __fsub_rn(Lneg, L);
    key1[(size_t)b * Nn + n] = pack_key(sigmoid_exp(d), n);
  } else if (e == 2) {
    out0[(size_t)b * (2 * Nn) + Nn + n] = L;
  }
}

// ------- top-k: ascending bitonic sort of packed u64 keys (verified ≡ brute-force) -----
template <int S>
__global__ void topk_bitonic(const unsigned long long* __restrict__ keysrc,
                             int* __restrict__ idx_out) {
  constexpr int K = S / 2;
  __shared__ unsigned long long keys[S];
  int b = blockIdx.x;
  for (int i = threadIdx.x; i < S; i += blockDim.x)
    keys[i] = keysrc[(size_t)b * S + i];
  for (int k = 2; k <= S; k <<= 1) {
    for (int j = k >> 1; j > 0; j >>= 1) {
      __syncthreads();
      for (int t = threadIdx.x; t < S / 2; t += blockDim.x) {
        int i = ((t / j) * (j << 1)) + (t % j);
        unsigned long long a = keys[i], c = keys[i + j];
        if (((i & k) == 0) == (a > c)) { keys[i] = c; keys[i + j] = a; }
      }
    }
  }
  __syncthreads();
  for (int t = threadIdx.x; t < K; t += blockDim.x)
    idx_out[(size_t)b * K + t] = (int)(keys[t] & 0xffffffffu);
}

// ---------------- per-column sort across batch (jnp.sort axis=0) ----------------
__global__ void colsort_kernel(const int* __restrict__ idx, int* __restrict__ sidx, int K) {
  int j = blockIdx.x * blockDim.x + threadIdx.x;
  if (j >= K) return;
  int v[16];
  for (int b = 0; b < 16; ++b) v[b] = idx[b * K + j];
  for (int a = 1; a < 16; ++a) {
    int x = v[a]; int c = a - 1;
    while (c >= 0 && v[c] > x) { v[c + 1] = v[c]; --c; }
    v[c + 1] = x;
  }
  for (int b = 0; b < 16; ++b) sidx[b * K + j] = v[b];
}

// ------- selected-row matmul v5: np3 tiling (2x4, 32 rows, 3 blocks/CU) + f4 staging ---
// Bit-exact m-ascending FMA chains unchanged. Staging: 12 b128 loads/thread/m-tile
// (was 48 scalar in np3). ash[32][132]: row stride 528B = 33*16 -> float4-aligned.
__global__ __launch_bounds__(256) void selmm_np5(const float* __restrict__ M,
                                                 const float* __restrict__ P,
                                                 const int* __restrict__ sidx,
                                                 float* __restrict__ L) {
  __shared__ __align__(16) float ash[32][132];
  __shared__ __align__(16) float psh[128][64];
  __shared__ int rj[32];
  int b = blockIdx.y, j0 = blockIdx.x * 32, t = threadIdx.x;
  if (t < 32) rj[t] = sidx[b * K1 + j0 + t];
  __syncthreads();
  int cg = t & 15, rg = t >> 4;      // 16 col-groups x 16 row-groups
  int r0 = rg * 2, r1 = r0 + 1;
  const float* Mb = M + (size_t)b * Nn * Nn;
  const float* Pb = P + (size_t)b * Nn * NHn;
  float acc00 = 0.f, acc01 = 0.f, acc02 = 0.f, acc03 = 0.f;
  float acc10 = 0.f, acc11 = 0.f, acc12 = 0.f, acc13 = 0.f;
  for (int m0 = 0; m0 < Nn; m0 += 128) {
    // ash: 32 rows x 128 cols = 1024 float4 / 256 threads = 4 passes
#pragma unroll
    for (int pass = 0; pass < 4; ++pass) {
      int f = pass * 256 + t;
      int row = f >> 5, c4 = f & 31;
      *(float4*)&ash[row][c4 * 4] = *(const float4*)&Mb[(size_t)rj[row] * Nn + m0 + c4 * 4];
    }
    // psh: 128 x 64 = 2048 float4 / 256 threads = 8 passes
#pragma unroll
    for (int pass = 0; pass < 8; ++pass) {
      int f = pass * 256 + t;
      int mm = f >> 4, c4 = f & 15;
      *(float4*)&psh[mm][c4 * 4] = *(const float4*)&Pb[(size_t)(m0 + mm) * NHn + c4 * 4];
    }
    __syncthreads();
#pragma unroll 4
    for (int mb = 0; mb < 32; ++mb) {
      float4 a0 = *(const float4*)&ash[r0][mb * 4];
      float4 a1 = *(const float4*)&ash[r1][mb * 4];
      float4 pv0 = *(const float4*)&psh[mb * 4 + 0][cg * 4];
      float4 pv1 = *(const float4*)&psh[mb * 4 + 1][cg * 4];
      float4 pv2 = *(const float4*)&psh[mb * 4 + 2][cg * 4];
      float4 pv3 = *(const float4*)&psh[mb * 4 + 3][cg * 4];
      // mm ascending per accumulator chain (bit-exact)
      acc00 = __fmaf_rn(a0.x, pv0.x, acc00);
      acc01 = __fmaf_rn(a0.x, pv0.y, acc01);
      acc02 = __fmaf_rn(a0.x, pv0.z, acc02);
      acc03 = __fmaf_rn(a0.x, pv0.w, acc03);
      acc10 = __fmaf_rn(a1.x, pv0.x, acc10);
      acc11 = __fmaf_rn(a1.x, pv0.y, acc11);
      acc12 = __fmaf_rn(a1.x, pv0.z, acc12);
      acc13 = __fmaf_rn(a1.x, pv0.w, acc13);
      acc00 = __fmaf_rn(a0.y, pv1.x, acc00);
      acc01 = __fmaf_rn(a0.y, pv1.y, acc01);
      acc02 = __fmaf_rn(a0.y, pv1.z, acc02);
      acc03 = __fmaf_rn(a0.y, pv1.w, acc03);
      acc10 = __fmaf_rn(a1.y, pv1.x, acc10);
      acc11 = __fmaf_rn(a1.y, pv1.y, acc11);
      acc12 = __fmaf_rn(a1.y, pv1.z, acc12);
      acc13 = __fmaf_rn(a1.y, pv1.w, acc13);
      acc00 = __fmaf_rn(a0.z, pv2.x, acc00);
      acc01 = __fmaf_rn(a0.z, pv2.y, acc01);
      acc02 = __fmaf_rn(a0.z, pv2.z, acc02);
      acc03 = __fmaf_rn(a0.z, pv2.w, acc03);
      acc10 = __fmaf_rn(a1.z, pv2.x, acc10);
      acc11 = __fmaf_rn(a1.z, pv2.y, acc11);
      acc12 = __fmaf_rn(a1.z, pv2.z, acc12);
      acc13 = __fmaf_rn(a1.z, pv2.w, acc13);
      acc00 = __fmaf_rn(a0.w, pv3.x, acc00);
      acc01 = __fmaf_rn(a0.w, pv3.y, acc01);
      acc02 = __fmaf_rn(a0.w, pv3.z, acc02);
      acc03 = __fmaf_rn(a0.w, pv3.w, acc03);
      acc10 = __fmaf_rn(a1.w, pv3.x, acc10);
      acc11 = __fmaf_rn(a1.w, pv3.y, acc11);
      acc12 = __fmaf_rn(a1.w, pv3.z, acc12);
      acc13 = __fmaf_rn(a1.w, pv3.w, acc13);
    }
    __syncthreads();
  }
  size_t base0 = ((size_t)b * K1 + j0 + r0) * NHn + cg * 4;
  size_t base1 = ((size_t)b * K1 + j0 + r1) * NHn + cg * 4;
  L[base0 + 0] = sigmoid_exp(acc00);
  L[base0 + 1] = sigmoid_exp(acc01);
  L[base0 + 2] = sigmoid_exp(acc02);
  L[base0 + 3] = sigmoid_exp(acc03);
  L[base1 + 0] = sigmoid_exp(acc10);
  L[base1 + 1] = sigmoid_exp(acc11);
  L[base1 + 2] = sigmoid_exp(acc12);
  L[base1 + 3] = sigmoid_exp(acc13);
}

// -------- cascade-2: Eigen-FMA stage1 (float4 w from LDS) + sequential mul/add stage2 --
__global__ __launch_bounds__(256) void logits2_np(
    const float* __restrict__ p1, const float* __restrict__ p2,
    const float* __restrict__ neg1, const float* __restrict__ neg2,
    const float* __restrict__ mask1, const float* __restrict__ mask2,
    const int* __restrict__ sidx1,
    const float* __restrict__ l1, const float* __restrict__ l2,
    const float* __restrict__ W1, const float* __restrict__ b1p,
    const float* __restrict__ betap,
    float* __restrict__ out1, unsigned long long* __restrict__ key2) {
  __shared__ __align__(16) float xp[64][68], xn[64][68], y1s[64][68], y2s[64][68], w[4096];
  __shared__ int rrs[64];
  int b = blockIdx.y, j0 = blockIdx.x * 64, t = threadIdx.x;
  if (t < 64) rrs[t] = sidx1[b * K1 + j0 + t];
  __syncthreads();
  for (int c = 0; c < 16; ++c) {
    int idx = c * 256 + t, row = idx >> 6, i = idx & 63;
    int rr = rrs[row];
    size_t ga = ((size_t)b * Nn + rr) * NHn + i;
    int ma = rr * NHn + i;
    xp[row][i] = __fmul_rn(__fadd_rn(p1[ga], p2[ga]), 0.5f);
    float nv1 = (mask1[ma] != 0.0f) ? 0.0f : neg1[ga];
    float nv2 = (mask2[ma] != 0.0f) ? 0.0f : neg2[ga];
    xn[row][i] = __fmul_rn(__fadd_rn(nv1, nv2), 0.5f);
    size_t la = ((size_t)b * K1 + j0 + row) * NHn + i;
    y1s[row][i] = l1[la];
    y2s[row][i] = l2[la];
    w[idx] = W1[idx];
  }
  __syncthreads();
  int row = t >> 2, e = t & 3;
  const float* x = (e & 2) ? &xn[row][0] : &xp[row][0];
  const float* yy = (e & 1) ? &y2s[row][0] : &y1s[row][0];
  float T[64];
#pragma unroll
  for (int j = 0; j < 64; ++j) T[j] = 0.0f;
  for (int i = 0; i < 64; ++i) {
    float xv = x[i];
#pragma unroll
    for (int jb = 0; jb < 16; ++jb) {
      float4 wv = *(const float4*)&w[i * 64 + jb * 4];
      T[jb * 4 + 0] = __fmaf_rn(xv, wv.x, T[jb * 4 + 0]);
      T[jb * 4 + 1] = __fmaf_rn(xv, wv.y, T[jb * 4 + 1]);
      T[jb * 4 + 2] = __fmaf_rn(xv, wv.z, T[jb * 4 + 2]);
      T[jb * 4 + 3] = __fmaf_rn(xv, wv.w, T[jb * 4 + 3]);
    }
  }
  float acc = 0.0f;
#pragma unroll
  for (int jb = 0; jb < 16; ++jb) {
    float4 yv = *(const float4*)&yy[jb * 4];
    acc = __fadd_rn(acc, __fmul_rn(T[jb * 4 + 0], yv.x));
    acc = __fadd_rn(acc, __fmul_rn(T[jb * 4 + 1], yv.y));
    acc = __fadd_rn(acc, __fmul_rn(T[jb * 4 + 2], yv.z));
    acc = __fadd_rn(acc, __fmul_rn(T[jb * 4 + 3], yv.w));
  }
  float a = __fadd_rn(acc, *b1p);
  float be = *betap, om = __fsub_rn(1.0f, be);
  float other = __shfl_xor(a, 1);
  float L = __fadd_rn(__fmul_rn(be, a), __fmul_rn(om, other));
  float Lneg = __shfl_xor(L, 2);
  int j = j0 + row;
  if (e == 0) {
    out1[(size_t)b * (2 * K1) + j] = L;
    float d = __fsub_rn(Lneg, L);
    key2[(size_t)b * K1 + j] = pack_key(sigmoid_exp(d), j);
  } else if (e == 2) {
    out1[(size_t)b * (2 * K1) + K1 + j] = L;
  }
}

// ---------------- cascade-3 logits (values only; 0.2587 slack) ----------------
__global__ void logits3_kernel(const float* __restrict__ p1, const float* __restrict__ p2,
                               const float* __restrict__ neg1, const float* __restrict__ neg2,
                               const float* __restrict__ mask1, const float* __restrict__ mask2,
                               const int* __restrict__ sidx1, const int* __restrict__ sidx2,
                               const float* __restrict__ W2,
                               const float* __restrict__ b2p, const float* __restrict__ lamp,
                               float* __restrict__ out2) {
  int b = blockIdx.y, tt = blockIdx.x, h = threadIdx.x;  // 64 threads
  int rr = sidx1[b * K1 + sidx2[b * K2 + tt]];
  __shared__ float XP[64], XN[64];
  size_t xb = ((size_t)b * Nn + rr) * NHn + h;
  int ma = rr * NHn + h;
  float pv1 = p1[xb], pv2 = p2[xb];
  float nv1 = (mask1[ma] != 0.0f) ? 0.0f : neg1[xb];
  float nv2 = (mask2[ma] != 0.0f) ? 0.0f : neg2[xb];
  XP[h] = (pv1 + pv2) * 0.5f;
  XN[h] = (nv1 + nv2) * 0.5f;
  __syncthreads();
  float tp = 0.f, tn = 0.f;
#pragma unroll 8
  for (int i = 0; i < 64; ++i) {
    float ww = W2[i * 64 + h];
    tp = fmaf(XP[i], ww, tp);
    tn = fmaf(XN[i], ww, tn);
  }
  float y1 = sigmoid_exp(pv1);
  float y2 = sigmoid_exp(pv2);
  float p11 = tp * y1, p12 = tp * y2, p21 = tn * y1, p22 = tn * y2;
  for (int o = 32; o > 0; o >>= 1) {
    p11 += __shfl_down(p11, o);
    p12 += __shfl_down(p12, o);
    p21 += __shfl_down(p21, o);
    p22 += __shfl_down(p22, o);
  }
  if (h == 0) {
    float bb = *b2p, lm = *lamp;
    out2[(size_t)b * (2 * K2) + tt]      = lm * (p11 + bb) + (1.0f - lm) * (p12 + bb);
    out2[(size_t)b * (2 * K2) + K2 + tt] = lm * (p21 + bb) + (1.0f - lm) * (p22 + bb);
  }
}

// ---------------- host ----------------
extern "C" void kernel_launch(void* const* d_in, const int* in_sizes, int n_in,
                              void* d_out, int out_size, void* d_ws, size_t ws_size,
                              hipStream_t stream) {
  (void)in_sizes; (void)n_in; (void)out_size; (void)ws_size;

  const float* adj   = (const float*)d_in[0];
  const float* diff  = (const float*)d_in[1];
  const float* pos1  = (const float*)d_in[2];
  const float* pos2  = (const float*)d_in[3];
  const float* neg1  = (const float*)d_in[4];
  const float* neg2  = (const float*)d_in[5];
  const float* W0    = (const float*)d_in[6];
  const float* b0    = (const float*)d_in[7];
  const float* W1    = (const float*)d_in[8];
  const float* b1    = (const float*)d_in[9];
  const float* W2    = (const float*)d_in[10];
  const float* b2    = (const float*)d_in[11];
  const float* alpha = (const float*)d_in[12];
  const float* beta  = (const float*)d_in[13];
  const float* lamda = (const float*)d_in[14];

  float* out0 = (float*)d_out;           // [16, 4096]
  float* out1 = out0 + Bn * 2 * Nn;      // [16, 2048]
  float* out2 = out1 + Bn * 2 * K1;      // [16, 1024]

  char* w = (char*)d_ws;
  size_t off = 0;
  auto alloc = [&](size_t bytes) -> void* {
    void* p = w + off;
    off += (bytes + 255) & ~(size_t)255;
    return p;
  };
  float* mask1 = (float*)alloc((size_t)Nn * NHn * 4);
  float* mask2 = (float*)alloc((size_t)Nn * NHn * 4);
  float* p1    = (float*)alloc((size_t)Bn * Nn * NHn * 4);
  float* p2    = (float*)alloc((size_t)Bn * Nn * NHn * 4);
  float* g1    = (float*)alloc((size_t)Bn * 64 * 4);
  float* g2    = (float*)alloc((size_t)Bn * 64 * 4);
  unsigned long long* key1 = (unsigned long long*)alloc((size_t)Bn * Nn * 8);
  unsigned long long* key2 = (unsigned long long*)alloc((size_t)Bn * K1 * 8);
  int*   idx1  = (int*)alloc((size_t)Bn * K1 * 4);
  int*   sidx1 = (int*)alloc((size_t)Bn * K1 * 4);
  int*   idx2  = (int*)alloc((size_t)Bn * K2 * 4);
  int*   sidx2 = (int*)alloc((size_t)Bn * K2 * 4);
  float* l1    = (float*)alloc((size_t)Bn * K1 * NHn * 4);
  float* l2    = (float*)alloc((size_t)Bn * K1 * NHn * 4);

  uint32_t fk0a = 0u, fk1a = 0u;
  { uint32_t x0 = 0u, x1 = 0u; tf2x32(0u, 1u, x0, x1); fk0a = x0; fk1a = x1; }
  uint32_t fk0b = 0u, fk1b = 0u;
  { uint32_t x0 = 0u, x1 = 1u; tf2x32(0u, 1u, x0, x1); fk0b = x0; fk1b = x1; }

  mask_kernel<<<(Nn * NHn + 255) / 256, 256, 0, stream>>>(fk0a, fk1a, fk0b, fk1b, mask1, mask2);

  drop_kernel<<<(Bn * Nn * NHn / 4) / 256, 256, 0, stream>>>(
      (const float4*)pos1, (const float4*)pos2, (const float4*)mask1, (const float4*)mask2,
      (float4*)p1, (float4*)p2);

  gmean_kernel<<<Bn, 64, 0, stream>>>(p1, p2, g1, g2);

  logits1_np<<<dim3(Nn / 64, Bn), 256, 0, stream>>>(p1, p2, neg1, neg2, mask1, mask2,
                                                    g1, g2, W0, b0, alpha, out0, key1);

  topk_bitonic<2048><<<Bn, 1024, 0, stream>>>(key1, idx1);
  colsort_kernel<<<K1 / 256, 256, 0, stream>>>(idx1, sidx1, K1);

  selmm_np5<<<dim3(K1 / 32, Bn), 256, 0, stream>>>(adj, p1, sidx1, l1);
  selmm_np5<<<dim3(K1 / 32, Bn), 256, 0, stream>>>(diff, p2, sidx1, l2);

  logits2_np<<<dim3(K1 / 64, Bn), 256, 0, stream>>>(p1, p2, neg1, neg2, mask1, mask2,
                                                    sidx1, l1, l2, W1, b1, beta, out1, key2);

  topk_bitonic<1024><<<Bn, 512, 0, stream>>>(key2, idx2);
  colsort_kernel<<<K2 / 256, 256, 0, stream>>>(idx2, sidx2, K2);

  logits3_kernel<<<dim3(K2, Bn), 64, 0, stream>>>(p1, p2, neg1, neg2, mask1, mask2,
                                                  sidx1, sidx2, W2, b2, lamda, out2);
}

// Round 17
// 333.562 us; speedup vs baseline: 1.1936x; 1.0134x over previous
//
#include <hip/hip_runtime.h>
#include <cstdint>
#include <cstddef>

static constexpr int Bn  = 16;
static constexpr int Nn  = 2048;
static constexpr int NHn = 64;
static constexpr int K1  = 1024;
static constexpr int K2  = 512;

// ---------------- threefry2x32 (exact JAX semantics; verified via out0) ----------------
__host__ __device__ inline void tf2x32(uint32_t k0, uint32_t k1, uint32_t& x0, uint32_t& x1) {
  const uint32_t ks0 = k0, ks1 = k1, ks2 = k0 ^ k1 ^ 0x1BD11BDAu;
  x0 += ks0; x1 += ks1;
  const int R[20] = {13,15,26,6, 17,29,16,24, 13,15,26,6, 17,29,16,24, 13,15,26,6};
  const uint32_t ks[3] = {ks0, ks1, ks2};
  int inj = 0;
  for (int r = 0; r < 20; ++r) {
    x0 += x1;
    x1 = (x1 << R[r]) | (x1 >> (32 - R[r]));
    x1 ^= x0;
    if ((r & 3) == 3) {
      ++inj;
      x0 += ks[inj % 3];
      x1 += ks[(inj + 1) % 3] + (uint32_t)inj;
    }
  }
}

// ---------------- XLA CPU f32 exp (GenerateVF32Exp / Eigen pexp, Cephes, FMA) ----------
__device__ __forceinline__ float xla_expf(float x) {
  const float LOG2EF   = 1.44269504088896341f;
  const float ln2_hi   = 0.693359375f;
  const float nln2_lo  = 2.12194440e-4f;     // -(ln2 - ln2_hi)
  const float p0 = 1.9875691500e-4f, p1c = 1.3981999507e-3f, p2c = 8.3334519073e-3f,
              p3c = 4.1665795894e-2f, p4c = 1.6666665459e-1f, p5c = 5.0000001201e-1f;
  float xc = fminf(fmaxf(x, -87.33654785f), 88.72283935f);
  float m = floorf(__fmaf_rn(xc, LOG2EF, 0.5f));
  float r = __fmaf_rn(m, -ln2_hi, xc);
  r = __fmaf_rn(m, nln2_lo, r);
  float r2 = __fmul_rn(r, r);
  float y = p0;
  y = __fmaf_rn(y, r, p1c);
  y = __fmaf_rn(y, r, p2c);
  y = __fmaf_rn(y, r, p3c);
  y = __fmaf_rn(y, r, p4c);
  y = __fmaf_rn(y, r, p5c);
  y = __fmaf_rn(y, r2, r);
  y = __fadd_rn(y, 1.0f);
  int n = (int)m;
  float s2 = __uint_as_float((uint32_t)(n + 127) << 23);  // exact 2^n (n in normal range here)
  return __fmul_rn(y, s2);
}

// XLA LogisticExpander (current): logistic(x) = 1 / (1 + exp(-x))
__device__ __forceinline__ float sigmoid_exp(float x) {
  float e = xla_expf(-x);
  return __fdiv_rn(1.0f, __fadd_rn(1.0f, e));
}

__device__ __forceinline__ unsigned long long pack_key(float s, int idx) {
  // ascending sort == (s desc, idx asc); s in (0,1): positive floats bit-ordered
  return ((unsigned long long)(__float_as_uint(s) ^ 0xFFFFFFFFu) << 32) | (uint32_t)idx;
}

// ---------------- masks: 1.0 = DROPPED (u < 0.1) ----------------
__global__ void mask_kernel(uint32_t fk0a, uint32_t fk1a, uint32_t fk0b, uint32_t fk1b,
                            float* __restrict__ mask1, float* __restrict__ mask2) {
  int i = blockIdx.x * blockDim.x + threadIdx.x;
  if (i >= Nn * NHn) return;
  uint32_t x0 = 0u, x1 = (uint32_t)i;
  tf2x32(fk0a, fk1a, x0, x1);
  uint32_t bits = x0 ^ x1;
  float u = __uint_as_float((bits >> 9) | 0x3f800000u) - 1.0f;
  mask1[i] = (u < 0.1f) ? 1.0f : 0.0f;
  x0 = 0u; x1 = (uint32_t)i;
  tf2x32(fk0b, fk1b, x0, x1);
  bits = x0 ^ x1;
  u = __uint_as_float((bits >> 9) | 0x3f800000u) - 1.0f;
  mask2[i] = (u < 0.1f) ? 1.0f : 0.0f;
}

// ---------------- dropout: p = where(m, 0, pos), float4 ----------------
__global__ void drop_kernel(const float4* __restrict__ pos1, const float4* __restrict__ pos2,
                            const float4* __restrict__ mask1, const float4* __restrict__ mask2,
                            float4* __restrict__ p1, float4* __restrict__ p2) {
  size_t i4 = (size_t)blockIdx.x * blockDim.x + threadIdx.x;  // grid covers B*N*NH/4
  int nh4 = (int)(i4 & (size_t)(Nn * NHn / 4 - 1));
  float4 m1 = mask1[nh4], m2 = mask2[nh4];
  float4 a = pos1[i4], c = pos2[i4];
  float4 o1, o2;
  o1.x = (m1.x != 0.0f) ? 0.0f : a.x;  o1.y = (m1.y != 0.0f) ? 0.0f : a.y;
  o1.z = (m1.z != 0.0f) ? 0.0f : a.z;  o1.w = (m1.w != 0.0f) ? 0.0f : a.w;
  o2.x = (m2.x != 0.0f) ? 0.0f : c.x;  o2.y = (m2.y != 0.0f) ? 0.0f : c.y;
  o2.z = (m2.z != 0.0f) ? 0.0f : c.z;  o2.w = (m2.w != 0.0f) ? 0.0f : c.w;
  p1[i4] = o1;
  p2[i4] = o2;
}

// ---------------- g = sigmoid(mean axis=1): sequential-n f32 reduce, then /2048 --------
__global__ void gmean_kernel(const float* __restrict__ p1, const float* __restrict__ p2,
                             float* __restrict__ g1, float* __restrict__ g2) {
  int b = blockIdx.x, h = threadIdx.x;  // 64 threads
  const float* P1 = p1 + (size_t)b * Nn * NHn + h;
  const float* P2 = p2 + (size_t)b * Nn * NHn + h;
  float a1 = 0.0f, a2 = 0.0f;
  for (int n = 0; n < Nn; n += 8) {
    float v1[8], v2[8];
#pragma unroll
    for (int u = 0; u < 8; ++u) {
      v1[u] = P1[(size_t)(n + u) * NHn];
      v2[u] = P2[(size_t)(n + u) * NHn];
    }
#pragma unroll
    for (int u = 0; u < 8; ++u) {
      a1 = __fadd_rn(a1, v1[u]);
      a2 = __fadd_rn(a2, v2[u]);
    }
  }
  float m1 = __fdiv_rn(a1, 2048.0f);  // exact pow2
  float m2 = __fdiv_rn(a2, 2048.0f);
  g1[b * 64 + h] = sigmoid_exp(m1);
  g2[b * 64 + h] = sigmoid_exp(m2);
}

// -------- cascade-1: Eigen-FMA stage1 (float4 w from LDS) + sequential mul/add stage2 --
__global__ __launch_bounds__(256) void logits1_np(
    const float* __restrict__ p1, const float* __restrict__ p2,
    const float* __restrict__ neg1, const float* __restrict__ neg2,
    const float* __restrict__ mask1, const float* __restrict__ mask2,
    const float* __restrict__ g1, const float* __restrict__ g2,
    const float* __restrict__ W0, const float* __restrict__ b0p,
    const float* __restrict__ alphap,
    float* __restrict__ out0, unsigned long long* __restrict__ key1) {
  __shared__ __align__(16) float xp[64][68], xn[64][68], w[4096], g[2][64];
  int b = blockIdx.y, n0 = blockIdx.x * 64, t = threadIdx.x;
  for (int c = 0; c < 16; ++c) {
    int idx = c * 256 + t, row = idx >> 6, i = idx & 63;
    size_t ga = ((size_t)b * Nn + n0 + row) * NHn + i;
    int ma = (n0 + row) * NHn + i;
    xp[row][i] = __fmul_rn(__fadd_rn(p1[ga], p2[ga]), 0.5f);
    float nv1 = (mask1[ma] != 0.0f) ? 0.0f : neg1[ga];
    float nv2 = (mask2[ma] != 0.0f) ? 0.0f : neg2[ga];
    xn[row][i] = __fmul_rn(__fadd_rn(nv1, nv2), 0.5f);
    w[idx] = W0[idx];
  }
  if (t < 64) { g[0][t] = g1[b * 64 + t]; g[1][t] = g2[b * 64 + t]; }
  __syncthreads();
  int row = t >> 2, e = t & 3;
  const float* x = (e & 2) ? &xn[row][0] : &xp[row][0];
  const float* gg = g[e & 1];
  // stage 1: T = x @ W0  (per-entry sequential i-ascending FMA chain; j chains indep.)
  float T[64];
#pragma unroll
  for (int j = 0; j < 64; ++j) T[j] = 0.0f;
  for (int i = 0; i < 64; ++i) {
    float xv = x[i];
#pragma unroll
    for (int jb = 0; jb < 16; ++jb) {
      float4 wv = *(const float4*)&w[i * 64 + jb * 4];
      T[jb * 4 + 0] = __fmaf_rn(xv, wv.x, T[jb * 4 + 0]);
      T[jb * 4 + 1] = __fmaf_rn(xv, wv.y, T[jb * 4 + 1]);
      T[jb * 4 + 2] = __fmaf_rn(xv, wv.z, T[jb * 4 + 2]);
      T[jb * 4 + 3] = __fmaf_rn(xv, wv.w, T[jb * 4 + 3]);
    }
  }
  // stage 2: sequential scalar j loop (separate mul/add), g read as float4 into regs
  float acc = 0.0f;
#pragma unroll
  for (int jb = 0; jb < 16; ++jb) {
    float4 gv = *(const float4*)&gg[jb * 4];
    acc = __fadd_rn(acc, __fmul_rn(T[jb * 4 + 0], gv.x));
    acc = __fadd_rn(acc, __fmul_rn(T[jb * 4 + 1], gv.y));
    acc = __fadd_rn(acc, __fmul_rn(T[jb * 4 + 2], gv.z));
    acc = __fadd_rn(acc, __fmul_rn(T[jb * 4 + 3], gv.w));
  }
  float a = __fadd_rn(acc, *b0p);
  float al = *alphap, om = __fsub_rn(1.0f, al);
  float other = __shfl_xor(a, 1);
  float L = __fadd_rn(__fmul_rn(al, a), __fmul_rn(om, other));
  float Lneg = __shfl_xor(L, 2);
  int n = n0 + row;
  if (e == 0) {
    out0[(size_t)b * (2 * Nn) + n] = L;
    float d = __fsub_rn(Lneg, L);
    key1[(size_t)b * Nn + n] = pack_key(sigmoid_exp(d), n);
  } else if (e == 2) {
    out0[(size_t)b * (2 * Nn) + Nn + n] = L;
  }
}

// ------- top-k: ascending bitonic sort of packed u64 keys (verified ≡ brute-force) -----
template <int S>
__global__ void topk_bitonic(const unsigned long long* __restrict__ keysrc,
                             int* __restrict__ idx_out) {
  constexpr int K = S / 2;
  __shared__ unsigned long long keys[S];
  int b = blockIdx.x;
  for (int i = threadIdx.x; i < S; i += blockDim.x)
    keys[i] = keysrc[(size_t)b * S + i];
  for (int k = 2; k <= S; k <<= 1) {
    for (int j = k >> 1; j > 0; j >>= 1) {
      __syncthreads();
      for (int t = threadIdx.x; t < S / 2; t += blockDim.x) {
        int i = ((t / j) * (j << 1)) + (t % j);
        unsigned long long a = keys[i], c = keys[i + j];
        if (((i & k) == 0) == (a > c)) { keys[i] = c; keys[i + j] = a; }
      }
    }
  }
  __syncthreads();
  for (int t = threadIdx.x; t < K; t += blockDim.x)
    idx_out[(size_t)b * K + t] = (int)(keys[t] & 0xffffffffu);
}

// ---------------- per-column sort across batch (jnp.sort axis=0) ----------------
__global__ void colsort_kernel(const int* __restrict__ idx, int* __restrict__ sidx, int K) {
  int j = blockIdx.x * blockDim.x + threadIdx.x;
  if (j >= K) return;
  int v[16];
  for (int b = 0; b < 16; ++b) v[b] = idx[b * K + j];
  for (int a = 1; a < 16; ++a) {
    int x = v[a]; int c = a - 1;
    while (c >= 0 && v[c] > x) { v[c + 1] = v[c]; --c; }
    v[c + 1] = x;
  }
  for (int b = 0; b < 16; ++b) sidx[b * K + j] = v[b];
}

// ------- selected-row matmul v6: np5 + z-merged (z=0: adj@p1->l1, z=1: diff@p2->l2) ----
// Bit-exact m-ascending FMA chains unchanged from np5.
__global__ __launch_bounds__(256) void selmm_np6(const float* __restrict__ M0,
                                                 const float* __restrict__ M1,
                                                 const float* __restrict__ P0,
                                                 const float* __restrict__ P1,
                                                 const int* __restrict__ sidx,
                                                 float* __restrict__ L0,
                                                 float* __restrict__ L1) {
  __shared__ __align__(16) float ash[32][132];
  __shared__ __align__(16) float psh[128][64];
  __shared__ int rj[32];
  int b = blockIdx.y, j0 = blockIdx.x * 32, t = threadIdx.x;
  const float* M = blockIdx.z ? M1 : M0;
  const float* P = blockIdx.z ? P1 : P0;
  float* L = blockIdx.z ? L1 : L0;
  if (t < 32) rj[t] = sidx[b * K1 + j0 + t];
  __syncthreads();
  int cg = t & 15, rg = t >> 4;      // 16 col-groups x 16 row-groups
  int r0 = rg * 2, r1 = r0 + 1;
  const float* Mb = M + (size_t)b * Nn * Nn;
  const float* Pb = P + (size_t)b * Nn * NHn;
  float acc00 = 0.f, acc01 = 0.f, acc02 = 0.f, acc03 = 0.f;
  float acc10 = 0.f, acc11 = 0.f, acc12 = 0.f, acc13 = 0.f;
  for (int m0 = 0; m0 < Nn; m0 += 128) {
    // ash: 32 rows x 128 cols = 1024 float4 / 256 threads = 4 passes
#pragma unroll
    for (int pass = 0; pass < 4; ++pass) {
      int f = pass * 256 + t;
      int row = f >> 5, c4 = f & 31;
      *(float4*)&ash[row][c4 * 4] = *(const float4*)&Mb[(size_t)rj[row] * Nn + m0 + c4 * 4];
    }
    // psh: 128 x 64 = 2048 float4 / 256 threads = 8 passes
#pragma unroll
    for (int pass = 0; pass < 8; ++pass) {
      int f = pass * 256 + t;
      int mm = f >> 4, c4 = f & 15;
      *(float4*)&psh[mm][c4 * 4] = *(const float4*)&Pb[(size_t)(m0 + mm) * NHn + c4 * 4];
    }
    __syncthreads();
#pragma unroll 4
    for (int mb = 0; mb < 32; ++mb) {
      float4 a0 = *(const float4*)&ash[r0][mb * 4];
      float4 a1 = *(const float4*)&ash[r1][mb * 4];
      float4 pv0 = *(const float4*)&psh[mb * 4 + 0][cg * 4];
      float4 pv1 = *(const float4*)&psh[mb * 4 + 1][cg * 4];
      float4 pv2 = *(const float4*)&psh[mb * 4 + 2][cg * 4];
      float4 pv3 = *(const float4*)&psh[mb * 4 + 3][cg * 4];
      // mm ascending per accumulator chain (bit-exact)
      acc00 = __fmaf_rn(a0.x, pv0.x, acc00);
      acc01 = __fmaf_rn(a0.x, pv0.y, acc01);
      acc02 = __fmaf_rn(a0.x, pv0.z, acc02);
      acc03 = __fmaf_rn(a0.x, pv0.w, acc03);
      acc10 = __fmaf_rn(a1.x, pv0.x, acc10);
      acc11 = __fmaf_rn(a1.x, pv0.y, acc11);
      acc12 = __fmaf_rn(a1.x, pv0.z, acc12);
      acc13 = __fmaf_rn(a1.x, pv0.w, acc13);
      acc00 = __fmaf_rn(a0.y, pv1.x, acc00);
      acc01 = __fmaf_rn(a0.y, pv1.y, acc01);
      acc02 = __fmaf_rn(a0.y, pv1.z, acc02);
      acc03 = __fmaf_rn(a0.y, pv1.w, acc03);
      acc10 = __fmaf_rn(a1.y, pv1.x, acc10);
      acc11 = __fmaf_rn(a1.y, pv1.y, acc11);
      acc12 = __fmaf_rn(a1.y, pv1.z, acc12);
      acc13 = __fmaf_rn(a1.y, pv1.w, acc13);
      acc00 = __fmaf_rn(a0.z, pv2.x, acc00);
      acc01 = __fmaf_rn(a0.z, pv2.y, acc01);
      acc02 = __fmaf_rn(a0.z, pv2.z, acc02);
      acc03 = __fmaf_rn(a0.z, pv2.w, acc03);
      acc10 = __fmaf_rn(a1.z, pv2.x, acc10);
      acc11 = __fmaf_rn(a1.z, pv2.y, acc11);
      acc12 = __fmaf_rn(a1.z, pv2.z, acc12);
      acc13 = __fmaf_rn(a1.z, pv2.w, acc13);
      acc00 = __fmaf_rn(a0.w, pv3.x, acc00);
      acc01 = __fmaf_rn(a0.w, pv3.y, acc01);
      acc02 = __fmaf_rn(a0.w, pv3.z, acc02);
      acc03 = __fmaf_rn(a0.w, pv3.w, acc03);
      acc10 = __fmaf_rn(a1.w, pv3.x, acc10);
      acc11 = __fmaf_rn(a1.w, pv3.y, acc11);
      acc12 = __fmaf_rn(a1.w, pv3.z, acc12);
      acc13 = __fmaf_rn(a1.w, pv3.w, acc13);
    }
    __syncthreads();
  }
  size_t base0 = ((size_t)b * K1 + j0 + r0) * NHn + cg * 4;
  size_t base1 = ((size_t)b * K1 + j0 + r1) * NHn + cg * 4;
  L[base0 + 0] = sigmoid_exp(acc00);
  L[base0 + 1] = sigmoid_exp(acc01);
  L[base0 + 2] = sigmoid_exp(acc02);
  L[base0 + 3] = sigmoid_exp(acc03);
  L[base1 + 0] = sigmoid_exp(acc10);
  L[base1 + 1] = sigmoid_exp(acc11);
  L[base1 + 2] = sigmoid_exp(acc12);
  L[base1 + 3] = sigmoid_exp(acc13);
}

// -------- cascade-2: Eigen-FMA stage1 (float4 w from LDS) + sequential mul/add stage2 --
__global__ __launch_bounds__(256) void logits2_np(
    const float* __restrict__ p1, const float* __restrict__ p2,
    const float* __restrict__ neg1, const float* __restrict__ neg2,
    const float* __restrict__ mask1, const float* __restrict__ mask2,
    const int* __restrict__ sidx1,
    const float* __restrict__ l1, const float* __restrict__ l2,
    const float* __restrict__ W1, const float* __restrict__ b1p,
    const float* __restrict__ betap,
    float* __restrict__ out1, unsigned long long* __restrict__ key2) {
  __shared__ __align__(16) float xp[64][68], xn[64][68], y1s[64][68], y2s[64][68], w[4096];
  __shared__ int rrs[64];
  int b = blockIdx.y, j0 = blockIdx.x * 64, t = threadIdx.x;
  if (t < 64) rrs[t] = sidx1[b * K1 + j0 + t];
  __syncthreads();
  for (int c = 0; c < 16; ++c) {
    int idx = c * 256 + t, row = idx >> 6, i = idx & 63;
    int rr = rrs[row];
    size_t ga = ((size_t)b * Nn + rr) * NHn + i;
    int ma = rr * NHn + i;
    xp[row][i] = __fmul_rn(__fadd_rn(p1[ga], p2[ga]), 0.5f);
    float nv1 = (mask1[ma] != 0.0f) ? 0.0f : neg1[ga];
    float nv2 = (mask2[ma] != 0.0f) ? 0.0f : neg2[ga];
    xn[row][i] = __fmul_rn(__fadd_rn(nv1, nv2), 0.5f);
    size_t la = ((size_t)b * K1 + j0 + row) * NHn + i;
    y1s[row][i] = l1[la];
    y2s[row][i] = l2[la];
    w[idx] = W1[idx];
  }
  __syncthreads();
  int row = t >> 2, e = t & 3;
  const float* x = (e & 2) ? &xn[row][0] : &xp[row][0];
  const float* yy = (e & 1) ? &y2s[row][0] : &y1s[row][0];
  float T[64];
#pragma unroll
  for (int j = 0; j < 64; ++j) T[j] = 0.0f;
  for (int i = 0; i < 64; ++i) {
    float xv = x[i];
#pragma unroll
    for (int jb = 0; jb < 16; ++jb) {
      float4 wv = *(const float4*)&w[i * 64 + jb * 4];
      T[jb * 4 + 0] = __fmaf_rn(xv, wv.x, T[jb * 4 + 0]);
      T[jb * 4 + 1] = __fmaf_rn(xv, wv.y, T[jb * 4 + 1]);
      T[jb * 4 + 2] = __fmaf_rn(xv, wv.z, T[jb * 4 + 2]);
      T[jb * 4 + 3] = __fmaf_rn(xv, wv.w, T[jb * 4 + 3]);
    }
  }
  float acc = 0.0f;
#pragma unroll
  for (int jb = 0; jb < 16; ++jb) {
    float4 yv = *(const float4*)&yy[jb * 4];
    acc = __fadd_rn(acc, __fmul_rn(T[jb * 4 + 0], yv.x));
    acc = __fadd_rn(acc, __fmul_rn(T[jb * 4 + 1], yv.y));
    acc = __fadd_rn(acc, __fmul_rn(T[jb * 4 + 2], yv.z));
    acc = __fadd_rn(acc, __fmul_rn(T[jb * 4 + 3], yv.w));
  }
  float a = __fadd_rn(acc, *b1p);
  float be = *betap, om = __fsub_rn(1.0f, be);
  float other = __shfl_xor(a, 1);
  float L = __fadd_rn(__fmul_rn(be, a), __fmul_rn(om, other));
  float Lneg = __shfl_xor(L, 2);
  int j = j0 + row;
  if (e == 0) {
    out1[(size_t)b * (2 * K1) + j] = L;
    float d = __fsub_rn(Lneg, L);
    key2[(size_t)b * K1 + j] = pack_key(sigmoid_exp(d), j);
  } else if (e == 2) {
    out1[(size_t)b * (2 * K1) + K1 + j] = L;
  }
}

// ---------------- cascade-3 logits (values only; 0.2587 slack) ----------------
__global__ void logits3_kernel(const float* __restrict__ p1, const float* __restrict__ p2,
                               const float* __restrict__ neg1, const float* __restrict__ neg2,
                               const float* __restrict__ mask1, const float* __restrict__ mask2,
                               const int* __restrict__ sidx1, const int* __restrict__ sidx2,
                               const float* __restrict__ W2,
                               const float* __restrict__ b2p, const float* __restrict__ lamp,
                               float* __restrict__ out2) {
  int b = blockIdx.y, tt = blockIdx.x, h = threadIdx.x;  // 64 threads
  int rr = sidx1[b * K1 + sidx2[b * K2 + tt]];
  __shared__ float XP[64], XN[64];
  size_t xb = ((size_t)b * Nn + rr) * NHn + h;
  int ma = rr * NHn + h;
  float pv1 = p1[xb], pv2 = p2[xb];
  float nv1 = (mask1[ma] != 0.0f) ? 0.0f : neg1[xb];
  float nv2 = (mask2[ma] != 0.0f) ? 0.0f : neg2[xb];
  XP[h] = (pv1 + pv2) * 0.5f;
  XN[h] = (nv1 + nv2) * 0.5f;
  __syncthreads();
  float tp = 0.f, tn = 0.f;
#pragma unroll 8
  for (int i = 0; i < 64; ++i) {
    float ww = W2[i * 64 + h];
    tp = fmaf(XP[i], ww, tp);
    tn = fmaf(XN[i], ww, tn);
  }
  float y1 = sigmoid_exp(pv1);
  float y2 = sigmoid_exp(pv2);
  float p11 = tp * y1, p12 = tp * y2, p21 = tn * y1, p22 = tn * y2;
  for (int o = 32; o > 0; o >>= 1) {
    p11 += __shfl_down(p11, o);
    p12 += __shfl_down(p12, o);
    p21 += __shfl_down(p21, o);
    p22 += __shfl_down(p22, o);
  }
  if (h == 0) {
    float bb = *b2p, lm = *lamp;
    out2[(size_t)b * (2 * K2) + tt]      = lm * (p11 + bb) + (1.0f - lm) * (p12 + bb);
    out2[(size_t)b * (2 * K2) + K2 + tt] = lm * (p21 + bb) + (1.0f - lm) * (p22 + bb);
  }
}

// ---------------- host ----------------
extern "C" void kernel_launch(void* const* d_in, const int* in_sizes, int n_in,
                              void* d_out, int out_size, void* d_ws, size_t ws_size,
                              hipStream_t stream) {
  (void)in_sizes; (void)n_in; (void)out_size; (void)ws_size;

  const float* adj   = (const float*)d_in[0];
  const float* diff  = (const float*)d_in[1];
  const float* pos1  = (const float*)d_in[2];
  const float* pos2  = (const float*)d_in[3];
  const float* neg1  = (const float*)d_in[4];
  const float* neg2  = (const float*)d_in[5];
  const float* W0    = (const float*)d_in[6];
  const float* b0    = (const float*)d_in[7];
  const float* W1    = (const float*)d_in[8];
  const float* b1    = (const float*)d_in[9];
  const float* W2    = (const float*)d_in[10];
  const float* b2    = (const float*)d_in[11];
  const float* alpha = (const float*)d_in[12];
  const float* beta  = (const float*)d_in[13];
  const float* lamda = (const float*)d_in[14];

  float* out0 = (float*)d_out;           // [16, 4096]
  float* out1 = out0 + Bn * 2 * Nn;      // [16, 2048]
  float* out2 = out1 + Bn * 2 * K1;      // [16, 1024]

  char* w = (char*)d_ws;
  size_t off = 0;
  auto alloc = [&](size_t bytes) -> void* {
    void* p = w + off;
    off += (bytes + 255) & ~(size_t)255;
    return p;
  };
  float* mask1 = (float*)alloc((size_t)Nn * NHn * 4);
  float* mask2 = (float*)alloc((size_t)Nn * NHn * 4);
  float* p1    = (float*)alloc((size_t)Bn * Nn * NHn * 4);
  float* p2    = (float*)alloc((size_t)Bn * Nn * NHn * 4);
  float* g1    = (float*)alloc((size_t)Bn * 64 * 4);
  float* g2    = (float*)alloc((size_t)Bn * 64 * 4);
  unsigned long long* key1 = (unsigned long long*)alloc((size_t)Bn * Nn * 8);
  unsigned long long* key2 = (unsigned long long*)alloc((size_t)Bn * K1 * 8);
  int*   idx1  = (int*)alloc((size_t)Bn * K1 * 4);
  int*   sidx1 = (int*)alloc((size_t)Bn * K1 * 4);
  int*   idx2  = (int*)alloc((size_t)Bn * K2 * 4);
  int*   sidx2 = (int*)alloc((size_t)Bn * K2 * 4);
  float* l1    = (float*)alloc((size_t)Bn * K1 * NHn * 4);
  float* l2    = (float*)alloc((size_t)Bn * K1 * NHn * 4);

  uint32_t fk0a = 0u, fk1a = 0u;
  { uint32_t x0 = 0u, x1 = 0u; tf2x32(0u, 1u, x0, x1); fk0a = x0; fk1a = x1; }
  uint32_t fk0b = 0u, fk1b = 0u;
  { uint32_t x0 = 0u, x1 = 1u; tf2x32(0u, 1u, x0, x1); fk0b = x0; fk1b = x1; }

  mask_kernel<<<(Nn * NHn + 255) / 256, 256, 0, stream>>>(fk0a, fk1a, fk0b, fk1b, mask1, mask2);

  drop_kernel<<<(Bn * Nn * NHn / 4) / 256, 256, 0, stream>>>(
      (const float4*)pos1, (const float4*)pos2, (const float4*)mask1, (const float4*)mask2,
      (float4*)p1, (float4*)p2);

  gmean_kernel<<<Bn, 64, 0, stream>>>(p1, p2, g1, g2);

  logits1_np<<<dim3(Nn / 64, Bn), 256, 0, stream>>>(p1, p2, neg1, neg2, mask1, mask2,
                                                    g1, g2, W0, b0, alpha, out0, key1);

  topk_bitonic<2048><<<Bn, 1024, 0, stream>>>(key1, idx1);
  colsort_kernel<<<K1 / 256, 256, 0, stream>>>(idx1, sidx1, K1);

  selmm_np6<<<dim3(K1 / 32, Bn, 2), 256, 0, stream>>>(adj, diff, p1, p2, sidx1, l1, l2);

  logits2_np<<<dim3(K1 / 64, Bn), 256, 0, stream>>>(p1, p2, neg1, neg2, mask1, mask2,
                                                    sidx1, l1, l2, W1, b1, beta, out1, key2);

  topk_bitonic<1024><<<Bn, 512, 0, stream>>>(key2, idx2);
  colsort_kernel<<<K2 / 256, 256, 0, stream>>>(idx2, sidx2, K2);

  logits3_kernel<<<dim3(K2, Bn), 64, 0, stream>>>(p1, p2, neg1, neg2, mask1, mask2,
                                                  sidx1, sidx2, W2, b2, lamda, out2);
}

// Round 18
// 329.556 us; speedup vs baseline: 1.2081x; 1.0122x over previous
//
#include <hip/hip_runtime.h>
#include <cstdint>
#include <cstddef>

static constexpr int Bn  = 16;
static constexpr int Nn  = 2048;
static constexpr int NHn = 64;
static constexpr int K1  = 1024;
static constexpr int K2  = 512;

// ---------------- threefry2x32 (exact JAX semantics; verified via out0) ----------------
__host__ __device__ inline void tf2x32(uint32_t k0, uint32_t k1, uint32_t& x0, uint32_t& x1) {
  const uint32_t ks0 = k0, ks1 = k1, ks2 = k0 ^ k1 ^ 0x1BD11BDAu;
  x0 += ks0; x1 += ks1;
  const int R[20] = {13,15,26,6, 17,29,16,24, 13,15,26,6, 17,29,16,24, 13,15,26,6};
  const uint32_t ks[3] = {ks0, ks1, ks2};
  int inj = 0;
  for (int r = 0; r < 20; ++r) {
    x0 += x1;
    x1 = (x1 << R[r]) | (x1 >> (32 - R[r]));
    x1 ^= x0;
    if ((r & 3) == 3) {
      ++inj;
      x0 += ks[inj % 3];
      x1 += ks[(inj + 1) % 3] + (uint32_t)inj;
    }
  }
}

// ---------------- XLA CPU f32 exp (GenerateVF32Exp / Eigen pexp, Cephes, FMA) ----------
__device__ __forceinline__ float xla_expf(float x) {
  const float LOG2EF   = 1.44269504088896341f;
  const float ln2_hi   = 0.693359375f;
  const float nln2_lo  = 2.12194440e-4f;     // -(ln2 - ln2_hi)
  const float p0 = 1.9875691500e-4f, p1c = 1.3981999507e-3f, p2c = 8.3334519073e-3f,
              p3c = 4.1665795894e-2f, p4c = 1.6666665459e-1f, p5c = 5.0000001201e-1f;
  float xc = fminf(fmaxf(x, -87.33654785f), 88.72283935f);
  float m = floorf(__fmaf_rn(xc, LOG2EF, 0.5f));
  float r = __fmaf_rn(m, -ln2_hi, xc);
  r = __fmaf_rn(m, nln2_lo, r);
  float r2 = __fmul_rn(r, r);
  float y = p0;
  y = __fmaf_rn(y, r, p1c);
  y = __fmaf_rn(y, r, p2c);
  y = __fmaf_rn(y, r, p3c);
  y = __fmaf_rn(y, r, p4c);
  y = __fmaf_rn(y, r, p5c);
  y = __fmaf_rn(y, r2, r);
  y = __fadd_rn(y, 1.0f);
  int n = (int)m;
  float s2 = __uint_as_float((uint32_t)(n + 127) << 23);  // exact 2^n (n in normal range here)
  return __fmul_rn(y, s2);
}

// XLA LogisticExpander (current): logistic(x) = 1 / (1 + exp(-x))
__device__ __forceinline__ float sigmoid_exp(float x) {
  float e = xla_expf(-x);
  return __fdiv_rn(1.0f, __fadd_rn(1.0f, e));
}

__device__ __forceinline__ unsigned long long pack_key(float s, int idx) {
  // ascending sort == (s desc, idx asc); s in (0,1): positive floats bit-ordered
  return ((unsigned long long)(__float_as_uint(s) ^ 0xFFFFFFFFu) << 32) | (uint32_t)idx;
}

// ---------------- masks: 1.0 = DROPPED (u < 0.1) ----------------
__global__ void mask_kernel(uint32_t fk0a, uint32_t fk1a, uint32_t fk0b, uint32_t fk1b,
                            float* __restrict__ mask1, float* __restrict__ mask2) {
  int i = blockIdx.x * blockDim.x + threadIdx.x;
  if (i >= Nn * NHn) return;
  uint32_t x0 = 0u, x1 = (uint32_t)i;
  tf2x32(fk0a, fk1a, x0, x1);
  uint32_t bits = x0 ^ x1;
  float u = __uint_as_float((bits >> 9) | 0x3f800000u) - 1.0f;
  mask1[i] = (u < 0.1f) ? 1.0f : 0.0f;
  x0 = 0u; x1 = (uint32_t)i;
  tf2x32(fk0b, fk1b, x0, x1);
  bits = x0 ^ x1;
  u = __uint_as_float((bits >> 9) | 0x3f800000u) - 1.0f;
  mask2[i] = (u < 0.1f) ? 1.0f : 0.0f;
}

// ---------------- dropout: p = where(m, 0, pos), float4 ----------------
__global__ void drop_kernel(const float4* __restrict__ pos1, const float4* __restrict__ pos2,
                            const float4* __restrict__ mask1, const float4* __restrict__ mask2,
                            float4* __restrict__ p1, float4* __restrict__ p2) {
  size_t i4 = (size_t)blockIdx.x * blockDim.x + threadIdx.x;  // grid covers B*N*NH/4
  int nh4 = (int)(i4 & (size_t)(Nn * NHn / 4 - 1));
  float4 m1 = mask1[nh4], m2 = mask2[nh4];
  float4 a = pos1[i4], c = pos2[i4];
  float4 o1, o2;
  o1.x = (m1.x != 0.0f) ? 0.0f : a.x;  o1.y = (m1.y != 0.0f) ? 0.0f : a.y;
  o1.z = (m1.z != 0.0f) ? 0.0f : a.z;  o1.w = (m1.w != 0.0f) ? 0.0f : a.w;
  o2.x = (m2.x != 0.0f) ? 0.0f : c.x;  o2.y = (m2.y != 0.0f) ? 0.0f : c.y;
  o2.z = (m2.z != 0.0f) ? 0.0f : c.z;  o2.w = (m2.w != 0.0f) ? 0.0f : c.w;
  p1[i4] = o1;
  p2[i4] = o2;
}

// ---------------- g = sigmoid(mean axis=1): sequential-n f32 reduce, then /2048 --------
__global__ void gmean_kernel(const float* __restrict__ p1, const float* __restrict__ p2,
                             float* __restrict__ g1, float* __restrict__ g2) {
  int b = blockIdx.x, h = threadIdx.x;  // 64 threads
  const float* P1 = p1 + (size_t)b * Nn * NHn + h;
  const float* P2 = p2 + (size_t)b * Nn * NHn + h;
  float a1 = 0.0f, a2 = 0.0f;
  for (int n = 0; n < Nn; n += 8) {
    float v1[8], v2[8];
#pragma unroll
    for (int u = 0; u < 8; ++u) {
      v1[u] = P1[(size_t)(n + u) * NHn];
      v2[u] = P2[(size_t)(n + u) * NHn];
    }
#pragma unroll
    for (int u = 0; u < 8; ++u) {
      a1 = __fadd_rn(a1, v1[u]);
      a2 = __fadd_rn(a2, v2[u]);
    }
  }
  float m1 = __fdiv_rn(a1, 2048.0f);  // exact pow2
  float m2 = __fdiv_rn(a2, 2048.0f);
  g1[b * 64 + h] = sigmoid_exp(m1);
  g2[b * 64 + h] = sigmoid_exp(m2);
}

// -------- cascade-1: Eigen-FMA stage1 (float4 w from LDS) + sequential mul/add stage2 --
__global__ __launch_bounds__(256) void logits1_np(
    const float* __restrict__ p1, const float* __restrict__ p2,
    const float* __restrict__ neg1, const float* __restrict__ neg2,
    const float* __restrict__ mask1, const float* __restrict__ mask2,
    const float* __restrict__ g1, const float* __restrict__ g2,
    const float* __restrict__ W0, const float* __restrict__ b0p,
    const float* __restrict__ alphap,
    float* __restrict__ out0, unsigned long long* __restrict__ key1) {
  __shared__ __align__(16) float xp[64][68], xn[64][68], w[4096], g[2][64];
  int b = blockIdx.y, n0 = blockIdx.x * 64, t = threadIdx.x;
  for (int c = 0; c < 16; ++c) {
    int idx = c * 256 + t, row = idx >> 6, i = idx & 63;
    size_t ga = ((size_t)b * Nn + n0 + row) * NHn + i;
    int ma = (n0 + row) * NHn + i;
    xp[row][i] = __fmul_rn(__fadd_rn(p1[ga], p2[ga]), 0.5f);
    float nv1 = (mask1[ma] != 0.0f) ? 0.0f : neg1[ga];
    float nv2 = (mask2[ma] != 0.0f) ? 0.0f : neg2[ga];
    xn[row][i] = __fmul_rn(__fadd_rn(nv1, nv2), 0.5f);
    w[idx] = W0[idx];
  }
  if (t < 64) { g[0][t] = g1[b * 64 + t]; g[1][t] = g2[b * 64 + t]; }
  __syncthreads();
  int row = t >> 2, e = t & 3;
  const float* x = (e & 2) ? &xn[row][0] : &xp[row][0];
  const float* gg = g[e & 1];
  // stage 1: T = x @ W0  (per-entry sequential i-ascending FMA chain; j chains indep.)
  float T[64];
#pragma unroll
  for (int j = 0; j < 64; ++j) T[j] = 0.0f;
  for (int i = 0; i < 64; ++i) {
    float xv = x[i];
#pragma unroll
    for (int jb = 0; jb < 16; ++jb) {
      float4 wv = *(const float4*)&w[i * 64 + jb * 4];
      T[jb * 4 + 0] = __fmaf_rn(xv, wv.x, T[jb * 4 + 0]);
      T[jb * 4 + 1] = __fmaf_rn(xv, wv.y, T[jb * 4 + 1]);
      T[jb * 4 + 2] = __fmaf_rn(xv, wv.z, T[jb * 4 + 2]);
      T[jb * 4 + 3] = __fmaf_rn(xv, wv.w, T[jb * 4 + 3]);
    }
  }
  // stage 2: sequential scalar j loop (separate mul/add), g read as float4 into regs
  float acc = 0.0f;
#pragma unroll
  for (int jb = 0; jb < 16; ++jb) {
    float4 gv = *(const float4*)&gg[jb * 4];
    acc = __fadd_rn(acc, __fmul_rn(T[jb * 4 + 0], gv.x));
    acc = __fadd_rn(acc, __fmul_rn(T[jb * 4 + 1], gv.y));
    acc = __fadd_rn(acc, __fmul_rn(T[jb * 4 + 2], gv.z));
    acc = __fadd_rn(acc, __fmul_rn(T[jb * 4 + 3], gv.w));
  }
  float a = __fadd_rn(acc, *b0p);
  float al = *alphap, om = __fsub_rn(1.0f, al);
  float other = __shfl_xor(a, 1);
  float L = __fadd_rn(__fmul_rn(al, a), __fmul_rn(om, other));
  float Lneg = __shfl_xor(L, 2);
  int n = n0 + row;
  if (e == 0) {
    out0[(size_t)b * (2 * Nn) + n] = L;
    float d = __fsub_rn(Lneg, L);
    key1[(size_t)b * Nn + n] = pack_key(sigmoid_exp(d), n);
  } else if (e == 2) {
    out0[(size_t)b * (2 * Nn) + Nn + n] = L;
  }
}

// ------- top-k: ascending bitonic sort of packed u64 keys (verified ≡ brute-force) -----
template <int S>
__global__ void topk_bitonic(const unsigned long long* __restrict__ keysrc,
                             int* __restrict__ idx_out) {
  constexpr int K = S / 2;
  __shared__ unsigned long long keys[S];
  int b = blockIdx.x;
  for (int i = threadIdx.x; i < S; i += blockDim.x)
    keys[i] = keysrc[(size_t)b * S + i];
  for (int k = 2; k <= S; k <<= 1) {
    for (int j = k >> 1; j > 0; j >>= 1) {
      __syncthreads();
      for (int t = threadIdx.x; t < S / 2; t += blockDim.x) {
        int i = ((t / j) * (j << 1)) + (t % j);
        unsigned long long a = keys[i], c = keys[i + j];
        if (((i & k) == 0) == (a > c)) { keys[i] = c; keys[i + j] = a; }
      }
    }
  }
  __syncthreads();
  for (int t = threadIdx.x; t < K; t += blockDim.x)
    idx_out[(size_t)b * K + t] = (int)(keys[t] & 0xffffffffu);
}

// ---------------- per-column sort across batch (jnp.sort axis=0) ----------------
__global__ void colsort_kernel(const int* __restrict__ idx, int* __restrict__ sidx, int K) {
  int j = blockIdx.x * blockDim.x + threadIdx.x;
  if (j >= K) return;
  int v[16];
  for (int b = 0; b < 16; ++b) v[b] = idx[b * K + j];
  for (int a = 1; a < 16; ++a) {
    int x = v[a]; int c = a - 1;
    while (c >= 0 && v[c] > x) { v[c + 1] = v[c]; --c; }
    v[c + 1] = x;
  }
  for (int b = 0; b < 16; ++b) sidx[b * K + j] = v[b];
}

// ------- selected-row matmul v7: np6 with m-tile 64 (LDS ~25KB -> 6 blocks/CU, no tail)
// Bit-exact m-ascending FMA chains unchanged. z=0: adj@p1->l1, z=1: diff@p2->l2.
__global__ __launch_bounds__(256) void selmm_np7(const float* __restrict__ M0,
                                                 const float* __restrict__ M1,
                                                 const float* __restrict__ P0,
                                                 const float* __restrict__ P1,
                                                 const int* __restrict__ sidx,
                                                 float* __restrict__ L0,
                                                 float* __restrict__ L1) {
  __shared__ __align__(16) float ash[32][68];   // 32 rows x 64 m (pad to 68: 272B = 17*16)
  __shared__ __align__(16) float psh[64][64];   // 64 m x 64 h
  __shared__ int rj[32];
  int b = blockIdx.y, j0 = blockIdx.x * 32, t = threadIdx.x;
  const float* M = blockIdx.z ? M1 : M0;
  const float* P = blockIdx.z ? P1 : P0;
  float* L = blockIdx.z ? L1 : L0;
  if (t < 32) rj[t] = sidx[b * K1 + j0 + t];
  __syncthreads();
  int cg = t & 15, rg = t >> 4;      // 16 col-groups x 16 row-groups
  int r0 = rg * 2, r1 = r0 + 1;
  const float* Mb = M + (size_t)b * Nn * Nn;
  const float* Pb = P + (size_t)b * Nn * NHn;
  float acc00 = 0.f, acc01 = 0.f, acc02 = 0.f, acc03 = 0.f;
  float acc10 = 0.f, acc11 = 0.f, acc12 = 0.f, acc13 = 0.f;
  for (int m0 = 0; m0 < Nn; m0 += 64) {
    // ash: 32 rows x 64 cols = 512 float4 / 256 threads = 2 passes
#pragma unroll
    for (int pass = 0; pass < 2; ++pass) {
      int f = pass * 256 + t;
      int row = f >> 4, c4 = f & 15;
      *(float4*)&ash[row][c4 * 4] = *(const float4*)&Mb[(size_t)rj[row] * Nn + m0 + c4 * 4];
    }
    // psh: 64 x 64 = 1024 float4 / 256 threads = 4 passes
#pragma unroll
    for (int pass = 0; pass < 4; ++pass) {
      int f = pass * 256 + t;
      int mm = f >> 4, c4 = f & 15;
      *(float4*)&psh[mm][c4 * 4] = *(const float4*)&Pb[(size_t)(m0 + mm) * NHn + c4 * 4];
    }
    __syncthreads();
#pragma unroll 4
    for (int mb = 0; mb < 16; ++mb) {
      float4 a0 = *(const float4*)&ash[r0][mb * 4];
      float4 a1 = *(const float4*)&ash[r1][mb * 4];
      float4 pv0 = *(const float4*)&psh[mb * 4 + 0][cg * 4];
      float4 pv1 = *(const float4*)&psh[mb * 4 + 1][cg * 4];
      float4 pv2 = *(const float4*)&psh[mb * 4 + 2][cg * 4];
      float4 pv3 = *(const float4*)&psh[mb * 4 + 3][cg * 4];
      // mm ascending per accumulator chain (bit-exact)
      acc00 = __fmaf_rn(a0.x, pv0.x, acc00);
      acc01 = __fmaf_rn(a0.x, pv0.y, acc01);
      acc02 = __fmaf_rn(a0.x, pv0.z, acc02);
      acc03 = __fmaf_rn(a0.x, pv0.w, acc03);
      acc10 = __fmaf_rn(a1.x, pv0.x, acc10);
      acc11 = __fmaf_rn(a1.x, pv0.y, acc11);
      acc12 = __fmaf_rn(a1.x, pv0.z, acc12);
      acc13 = __fmaf_rn(a1.x, pv0.w, acc13);
      acc00 = __fmaf_rn(a0.y, pv1.x, acc00);
      acc01 = __fmaf_rn(a0.y, pv1.y, acc01);
      acc02 = __fmaf_rn(a0.y, pv1.z, acc02);
      acc03 = __fmaf_rn(a0.y, pv1.w, acc03);
      acc10 = __fmaf_rn(a1.y, pv1.x, acc10);
      acc11 = __fmaf_rn(a1.y, pv1.y, acc11);
      acc12 = __fmaf_rn(a1.y, pv1.z, acc12);
      acc13 = __fmaf_rn(a1.y, pv1.w, acc13);
      acc00 = __fmaf_rn(a0.z, pv2.x, acc00);
      acc01 = __fmaf_rn(a0.z, pv2.y, acc01);
      acc02 = __fmaf_rn(a0.z, pv2.z, acc02);
      acc03 = __fmaf_rn(a0.z, pv2.w, acc03);
      acc10 = __fmaf_rn(a1.z, pv2.x, acc10);
      acc11 = __fmaf_rn(a1.z, pv2.y, acc11);
      acc12 = __fmaf_rn(a1.z, pv2.z, acc12);
      acc13 = __fmaf_rn(a1.z, pv2.w, acc13);
      acc00 = __fmaf_rn(a0.w, pv3.x, acc00);
      acc01 = __fmaf_rn(a0.w, pv3.y, acc01);
      acc02 = __fmaf_rn(a0.w, pv3.z, acc02);
      acc03 = __fmaf_rn(a0.w, pv3.w, acc03);
      acc10 = __fmaf_rn(a1.w, pv3.x, acc10);
      acc11 = __fmaf_rn(a1.w, pv3.y, acc11);
      acc12 = __fmaf_rn(a1.w, pv3.z, acc12);
      acc13 = __fmaf_rn(a1.w, pv3.w, acc13);
    }
    __syncthreads();
  }
  size_t base0 = ((size_t)b * K1 + j0 + r0) * NHn + cg * 4;
  size_t base1 = ((size_t)b * K1 + j0 + r1) * NHn + cg * 4;
  L[base0 + 0] = sigmoid_exp(acc00);
  L[base0 + 1] = sigmoid_exp(acc01);
  L[base0 + 2] = sigmoid_exp(acc02);
  L[base0 + 3] = sigmoid_exp(acc03);
  L[base1 + 0] = sigmoid_exp(acc10);
  L[base1 + 1] = sigmoid_exp(acc11);
  L[base1 + 2] = sigmoid_exp(acc12);
  L[base1 + 3] = sigmoid_exp(acc13);
}

// -------- cascade-2: Eigen-FMA stage1 (float4 w from LDS) + sequential mul/add stage2 --
__global__ __launch_bounds__(256) void logits2_np(
    const float* __restrict__ p1, const float* __restrict__ p2,
    const float* __restrict__ neg1, const float* __restrict__ neg2,
    const float* __restrict__ mask1, const float* __restrict__ mask2,
    const int* __restrict__ sidx1,
    const float* __restrict__ l1, const float* __restrict__ l2,
    const float* __restrict__ W1, const float* __restrict__ b1p,
    const float* __restrict__ betap,
    float* __restrict__ out1, unsigned long long* __restrict__ key2) {
  __shared__ __align__(16) float xp[64][68], xn[64][68], y1s[64][68], y2s[64][68], w[4096];
  __shared__ int rrs[64];
  int b = blockIdx.y, j0 = blockIdx.x * 64, t = threadIdx.x;
  if (t < 64) rrs[t] = sidx1[b * K1 + j0 + t];
  __syncthreads();
  for (int c = 0; c < 16; ++c) {
    int idx = c * 256 + t, row = idx >> 6, i = idx & 63;
    int rr = rrs[row];
    size_t ga = ((size_t)b * Nn + rr) * NHn + i;
    int ma = rr * NHn + i;
    xp[row][i] = __fmul_rn(__fadd_rn(p1[ga], p2[ga]), 0.5f);
    float nv1 = (mask1[ma] != 0.0f) ? 0.0f : neg1[ga];
    float nv2 = (mask2[ma] != 0.0f) ? 0.0f : neg2[ga];
    xn[row][i] = __fmul_rn(__fadd_rn(nv1, nv2), 0.5f);
    size_t la = ((size_t)b * K1 + j0 + row) * NHn + i;
    y1s[row][i] = l1[la];
    y2s[row][i] = l2[la];
    w[idx] = W1[idx];
  }
  __syncthreads();
  int row = t >> 2, e = t & 3;
  const float* x = (e & 2) ? &xn[row][0] : &xp[row][0];
  const float* yy = (e & 1) ? &y2s[row][0] : &y1s[row][0];
  float T[64];
#pragma unroll
  for (int j = 0; j < 64; ++j) T[j] = 0.0f;
  for (int i = 0; i < 64; ++i) {
    float xv = x[i];
#pragma unroll
    for (int jb = 0; jb < 16; ++jb) {
      float4 wv = *(const float4*)&w[i * 64 + jb * 4];
      T[jb * 4 + 0] = __fmaf_rn(xv, wv.x, T[jb * 4 + 0]);
      T[jb * 4 + 1] = __fmaf_rn(xv, wv.y, T[jb * 4 + 1]);
      T[jb * 4 + 2] = __fmaf_rn(xv, wv.z, T[jb * 4 + 2]);
      T[jb * 4 + 3] = __fmaf_rn(xv, wv.w, T[jb * 4 + 3]);
    }
  }
  float acc = 0.0f;
#pragma unroll
  for (int jb = 0; jb < 16; ++jb) {
    float4 yv = *(const float4*)&yy[jb * 4];
    acc = __fadd_rn(acc, __fmul_rn(T[jb * 4 + 0], yv.x));
    acc = __fadd_rn(acc, __fmul_rn(T[jb * 4 + 1], yv.y));
    acc = __fadd_rn(acc, __fmul_rn(T[jb * 4 + 2], yv.z));
    acc = __fadd_rn(acc, __fmul_rn(T[jb * 4 + 3], yv.w));
  }
  float a = __fadd_rn(acc, *b1p);
  float be = *betap, om = __fsub_rn(1.0f, be);
  float other = __shfl_xor(a, 1);
  float L = __fadd_rn(__fmul_rn(be, a), __fmul_rn(om, other));
  float Lneg = __shfl_xor(L, 2);
  int j = j0 + row;
  if (e == 0) {
    out1[(size_t)b * (2 * K1) + j] = L;
    float d = __fsub_rn(Lneg, L);
    key2[(size_t)b * K1 + j] = pack_key(sigmoid_exp(d), j);
  } else if (e == 2) {
    out1[(size_t)b * (2 * K1) + K1 + j] = L;
  }
}

// ---------------- cascade-3 logits (values only; 0.2587 slack) ----------------
__global__ void logits3_kernel(const float* __restrict__ p1, const float* __restrict__ p2,
                               const float* __restrict__ neg1, const float* __restrict__ neg2,
                               const float* __restrict__ mask1, const float* __restrict__ mask2,
                               const int* __restrict__ sidx1, const int* __restrict__ sidx2,
                               const float* __restrict__ W2,
                               const float* __restrict__ b2p, const float* __restrict__ lamp,
                               float* __restrict__ out2) {
  int b = blockIdx.y, tt = blockIdx.x, h = threadIdx.x;  // 64 threads
  int rr = sidx1[b * K1 + sidx2[b * K2 + tt]];
  __shared__ float XP[64], XN[64];
  size_t xb = ((size_t)b * Nn + rr) * NHn + h;
  int ma = rr * NHn + h;
  float pv1 = p1[xb], pv2 = p2[xb];
  float nv1 = (mask1[ma] != 0.0f) ? 0.0f : neg1[xb];
  float nv2 = (mask2[ma] != 0.0f) ? 0.0f : neg2[xb];
  XP[h] = (pv1 + pv2) * 0.5f;
  XN[h] = (nv1 + nv2) * 0.5f;
  __syncthreads();
  float tp = 0.f, tn = 0.f;
#pragma unroll 8
  for (int i = 0; i < 64; ++i) {
    float ww = W2[i * 64 + h];
    tp = fmaf(XP[i], ww, tp);
    tn = fmaf(XN[i], ww, tn);
  }
  float y1 = sigmoid_exp(pv1);
  float y2 = sigmoid_exp(pv2);
  float p11 = tp * y1, p12 = tp * y2, p21 = tn * y1, p22 = tn * y2;
  for (int o = 32; o > 0; o >>= 1) {
    p11 += __shfl_down(p11, o);
    p12 += __shfl_down(p12, o);
    p21 += __shfl_down(p21, o);
    p22 += __shfl_down(p22, o);
  }
  if (h == 0) {
    float bb = *b2p, lm = *lamp;
    out2[(size_t)b * (2 * K2) + tt]      = lm * (p11 + bb) + (1.0f - lm) * (p12 + bb);
    out2[(size_t)b * (2 * K2) + K2 + tt] = lm * (p21 + bb) + (1.0f - lm) * (p22 + bb);
  }
}

// ---------------- host ----------------
extern "C" void kernel_launch(void* const* d_in, const int* in_sizes, int n_in,
                              void* d_out, int out_size, void* d_ws, size_t ws_size,
                              hipStream_t stream) {
  (void)in_sizes; (void)n_in; (void)out_size; (void)ws_size;

  const float* adj   = (const float*)d_in[0];
  const float* diff  = (const float*)d_in[1];
  const float* pos1  = (const float*)d_in[2];
  const float* pos2  = (const float*)d_in[3];
  const float* neg1  = (const float*)d_in[4];
  const float* neg2  = (const float*)d_in[5];
  const float* W0    = (const float*)d_in[6];
  const float* b0    = (const float*)d_in[7];
  const float* W1    = (const float*)d_in[8];
  const float* b1    = (const float*)d_in[9];
  const float* W2    = (const float*)d_in[10];
  const float* b2    = (const float*)d_in[11];
  const float* alpha = (const float*)d_in[12];
  const float* beta  = (const float*)d_in[13];
  const float* lamda = (const float*)d_in[14];

  float* out0 = (float*)d_out;           // [16, 4096]
  float* out1 = out0 + Bn * 2 * Nn;      // [16, 2048]
  float* out2 = out1 + Bn * 2 * K1;      // [16, 1024]

  char* w = (char*)d_ws;
  size_t off = 0;
  auto alloc = [&](size_t bytes) -> void* {
    void* p = w + off;
    off += (bytes + 255) & ~(size_t)255;
    return p;
  };
  float* mask1 = (float*)alloc((size_t)Nn * NHn * 4);
  float* mask2 = (float*)alloc((size_t)Nn * NHn * 4);
  float* p1    = (float*)alloc((size_t)Bn * Nn * NHn * 4);
  float* p2    = (float*)alloc((size_t)Bn * Nn * NHn * 4);
  float* g1    = (float*)alloc((size_t)Bn * 64 * 4);
  float* g2    = (float*)alloc((size_t)Bn * 64 * 4);
  unsigned long long* key1 = (unsigned long long*)alloc((size_t)Bn * Nn * 8);
  unsigned long long* key2 = (unsigned long long*)alloc((size_t)Bn * K1 * 8);
  int*   idx1  = (int*)alloc((size_t)Bn * K1 * 4);
  int*   sidx1 = (int*)alloc((size_t)Bn * K1 * 4);
  int*   idx2  = (int*)alloc((size_t)Bn * K2 * 4);
  int*   sidx2 = (int*)alloc((size_t)Bn * K2 * 4);
  float* l1    = (float*)alloc((size_t)Bn * K1 * NHn * 4);
  float* l2    = (float*)alloc((size_t)Bn * K1 * NHn * 4);

  uint32_t fk0a = 0u, fk1a = 0u;
  { uint32_t x0 = 0u, x1 = 0u; tf2x32(0u, 1u, x0, x1); fk0a = x0; fk1a = x1; }
  uint32_t fk0b = 0u, fk1b = 0u;
  { uint32_t x0 = 0u, x1 = 1u; tf2x32(0u, 1u, x0, x1); fk0b = x0; fk1b = x1; }

  mask_kernel<<<(Nn * NHn + 255) / 256, 256, 0, stream>>>(fk0a, fk1a, fk0b, fk1b, mask1, mask2);

  drop_kernel<<<(Bn * Nn * NHn / 4) / 256, 256, 0, stream>>>(
      (const float4*)pos1, (const float4*)pos2, (const float4*)mask1, (const float4*)mask2,
      (float4*)p1, (float4*)p2);

  gmean_kernel<<<Bn, 64, 0, stream>>>(p1, p2, g1, g2);

  logits1_np<<<dim3(Nn / 64, Bn), 256, 0, stream>>>(p1, p2, neg1, neg2, mask1, mask2,
                                                    g1, g2, W0, b0, alpha, out0, key1);

  topk_bitonic<2048><<<Bn, 1024, 0, stream>>>(key1, idx1);
  colsort_kernel<<<K1 / 256, 256, 0, stream>>>(idx1, sidx1, K1);

  selmm_np7<<<dim3(K1 / 32, Bn, 2), 256, 0, stream>>>(adj, diff, p1, p2, sidx1, l1, l2);

  logits2_np<<<dim3(K1 / 64, Bn), 256, 0, stream>>>(p1, p2, neg1, neg2, mask1, mask2,
                                                    sidx1, l1, l2, W1, b1, beta, out1, key2);

  topk_bitonic<1024><<<Bn, 512, 0, stream>>>(key2, idx2);
  colsort_kernel<<<K2 / 256, 256, 0, stream>>>(idx2, sidx2, K2);

  logits3_kernel<<<dim3(K2, Bn), 64, 0, stream>>>(p1, p2, neg1, neg2, mask1, mask2,
                                                  sidx1, sidx2, W2, b2, lamda, out2);
}